// Round 1
// baseline (769.075 us; speedup 1.0000x reference)
//
#include <hip/hip_runtime.h>
#include <math.h>

constexpr float NEG_SLOPE = 0.2f;
constexpr float LN_EPS = 1e-5f;

// ---------------- CSR build ----------------

__global__ void k_zero(int* __restrict__ p, int n) {
    int i = blockIdx.x * blockDim.x + threadIdx.x;
    if (i < n) p[i] = 0;
}

__global__ void k_hist(const int* __restrict__ ei, int E, int N, int* __restrict__ cnt) {
    int i = blockIdx.x * blockDim.x + threadIdx.x;
    if (i >= E + N) return;
    int dst = (i < E) ? ei[E + i] : (i - E);
    atomicAdd(&cnt[dst], 1);
}

// single-block scan: offs[0]=0, offs[i+1]=sum(cnt[0..i])
__global__ void k_scan(const int* __restrict__ cnt, int* __restrict__ offs, int n) {
    __shared__ int buf[1024];
    __shared__ int carry_s;
    if (threadIdx.x == 0) { carry_s = 0; offs[0] = 0; }
    __syncthreads();
    for (int base = 0; base < n; base += 1024) {
        int i = base + (int)threadIdx.x;
        int v = (i < n) ? cnt[i] : 0;
        buf[threadIdx.x] = v;
        __syncthreads();
        for (int off = 1; off < 1024; off <<= 1) {
            int add = (threadIdx.x >= (unsigned)off) ? buf[threadIdx.x - off] : 0;
            __syncthreads();
            buf[threadIdx.x] += add;
            __syncthreads();
        }
        if (i < n) offs[i + 1] = carry_s + buf[threadIdx.x];
        __syncthreads();
        if (threadIdx.x == 0) carry_s += buf[1023];
        __syncthreads();
    }
}

__global__ void k_copy(const int* __restrict__ a, int* __restrict__ b, int n) {
    int i = blockIdx.x * blockDim.x + threadIdx.x;
    if (i < n) b[i] = a[i];
}

__global__ void k_scatter(const int* __restrict__ ei, int E, int N,
                          int* __restrict__ cursor, int* __restrict__ csr) {
    int i = blockIdx.x * blockDim.x + threadIdx.x;
    if (i >= E + N) return;
    int src, dst;
    if (i < E) { src = ei[i]; dst = ei[E + i]; }
    else       { src = i - E; dst = i - E; }
    int pos = atomicAdd(&cursor[dst], 1);
    csr[pos] = src;
}

// ---------------- GEMM h = X * W  (+ fused s,t scores) ----------------
// X: [N,K], W: [K,256], h: [N,256], s,t: [N,4]
// block = 256 threads; tile = 64 rows x 256 cols; thread = 8x8 register block.

template <int K>
__global__ __launch_bounds__(256) void k_gemm_st(
    const float* __restrict__ X, const float* __restrict__ W,
    const float* __restrict__ a_s, const float* __restrict__ a_d,
    float* __restrict__ h, float* __restrict__ s, float* __restrict__ t, int N)
{
    __shared__ float Xt[K][68];     // transposed X tile, padded
    __shared__ float Wl[32][256];   // W chunk (32 k-rows)

    const int tid = threadIdx.x;
    const int row0 = blockIdx.x * 64;

    // stage X transposed: scalar coalesced global reads, scalar LDS writes
    for (int idx = tid; idx < 64 * K; idx += 256) {
        int r = idx >> 6;            // wrong split would break coalescing; idx%? see below
        // re-map: consecutive idx -> consecutive k within a row
        r = idx / K;
        int k = idx - r * K;
        int row = row0 + r;
        float v = (row < N) ? X[(size_t)row * K + k] : 0.0f;
        Xt[k][r] = v;
    }

    const int tc = tid & 31;   // col group: cols 8*tc .. 8*tc+7
    const int tr = tid >> 5;   // row group: rows 8*tr .. 8*tr+7

    float acc[8][8];
#pragma unroll
    for (int i = 0; i < 8; ++i)
#pragma unroll
        for (int j = 0; j < 8; ++j) acc[i][j] = 0.0f;

    for (int k0 = 0; k0 < K; k0 += 32) {
        __syncthreads();
        // stage W chunk: 32x256 floats = 2048 float4 / 256 thr = 8 each
        for (int idx = tid; idx < 32 * 64; idx += 256) {
            int kk = idx >> 6;
            int c4 = idx & 63;
            *reinterpret_cast<float4*>(&Wl[kk][c4 * 4]) =
                *reinterpret_cast<const float4*>(W + (size_t)(k0 + kk) * 256 + c4 * 4);
        }
        __syncthreads();
#pragma unroll 4
        for (int kk = 0; kk < 32; ++kk) {
            const int k = k0 + kk;
            float4 xa = *reinterpret_cast<const float4*>(&Xt[k][8 * tr]);
            float4 xb = *reinterpret_cast<const float4*>(&Xt[k][8 * tr + 4]);
            float4 wa = *reinterpret_cast<const float4*>(&Wl[kk][8 * tc]);
            float4 wb = *reinterpret_cast<const float4*>(&Wl[kk][8 * tc + 4]);
            float xr[8] = {xa.x, xa.y, xa.z, xa.w, xb.x, xb.y, xb.z, xb.w};
            float wc[8] = {wa.x, wa.y, wa.z, wa.w, wb.x, wb.y, wb.z, wb.w};
#pragma unroll
            for (int i = 0; i < 8; ++i)
#pragma unroll
                for (int j = 0; j < 8; ++j)
                    acc[i][j] = fmaf(xr[i], wc[j], acc[i][j]);
        }
    }

    // epilogue: write h, fused s,t
    float4 asa = *reinterpret_cast<const float4*>(a_s + 8 * tc);
    float4 asb = *reinterpret_cast<const float4*>(a_s + 8 * tc + 4);
    float4 ada = *reinterpret_cast<const float4*>(a_d + 8 * tc);
    float4 adb = *reinterpret_cast<const float4*>(a_d + 8 * tc + 4);
    float asv[8] = {asa.x, asa.y, asa.z, asa.w, asb.x, asb.y, asb.z, asb.w};
    float adv[8] = {ada.x, ada.y, ada.z, ada.w, adb.x, adb.y, adb.z, adb.w};
    const int head = tc >> 3;

#pragma unroll
    for (int i = 0; i < 8; ++i) {
        int row = row0 + 8 * tr + i;
        if (row < N) {
            float4 o0 = make_float4(acc[i][0], acc[i][1], acc[i][2], acc[i][3]);
            float4 o1 = make_float4(acc[i][4], acc[i][5], acc[i][6], acc[i][7]);
            *reinterpret_cast<float4*>(h + (size_t)row * 256 + 8 * tc) = o0;
            *reinterpret_cast<float4*>(h + (size_t)row * 256 + 8 * tc + 4) = o1;
            float ps = 0.f, pt = 0.f;
#pragma unroll
            for (int j = 0; j < 8; ++j) {
                ps = fmaf(acc[i][j], asv[j], ps);
                pt = fmaf(acc[i][j], adv[j], pt);
            }
            ps += __shfl_xor(ps, 1); ps += __shfl_xor(ps, 2); ps += __shfl_xor(ps, 4);
            pt += __shfl_xor(pt, 1); pt += __shfl_xor(pt, 2); pt += __shfl_xor(pt, 4);
            if ((tc & 7) == 0) {
                s[(size_t)row * 4 + head] = ps;
                t[(size_t)row * 4 + head] = pt;
            }
        }
    }
}

// ---------------- aggregation (+ bias + LayerNorm + ELU) ----------------
// one wave per destination node; lane owns 4 channels; head = lane>>4

__global__ __launch_bounds__(256) void k_agg_ln_elu(
    const int* __restrict__ offs, const int* __restrict__ csr,
    const float* __restrict__ s, const float* __restrict__ t,
    const float* __restrict__ h, const float* __restrict__ bias,
    const float* __restrict__ lng, const float* __restrict__ lnb,
    float* __restrict__ Y, int N)
{
    const int wid = threadIdx.x >> 6;
    const int lane = threadIdx.x & 63;
    const int n = blockIdx.x * 4 + wid;
    if (n >= N) return;
    const int head = lane >> 4;
    const float tval = t[(size_t)n * 4 + head];
    const int beg = offs[n], end = offs[n + 1];

    float m = -1e30f;
    for (int i = beg; i < end; ++i) {
        int src = csr[i];
        float e = s[(size_t)src * 4 + head] + tval;
        e = (e > 0.f) ? e : NEG_SLOPE * e;
        m = fmaxf(m, e);
    }
    float den = 0.f;
    float4 acc = make_float4(0.f, 0.f, 0.f, 0.f);
    for (int i = beg; i < end; ++i) {
        int src = csr[i];
        float e = s[(size_t)src * 4 + head] + tval;
        e = (e > 0.f) ? e : NEG_SLOPE * e;
        float p = __expf(e - m);
        den += p;
        float4 hv = *reinterpret_cast<const float4*>(h + (size_t)src * 256 + lane * 4);
        acc.x = fmaf(p, hv.x, acc.x);
        acc.y = fmaf(p, hv.y, acc.y);
        acc.z = fmaf(p, hv.z, acc.z);
        acc.w = fmaf(p, hv.w, acc.w);
    }
    const float inv = 1.0f / den;
    float4 bv = *reinterpret_cast<const float4*>(bias + lane * 4);
    float v0 = acc.x * inv + bv.x;
    float v1 = acc.y * inv + bv.y;
    float v2 = acc.z * inv + bv.z;
    float v3 = acc.w * inv + bv.w;

    // LayerNorm over 256 features (held by this wave)
    float sum = v0 + v1 + v2 + v3;
#pragma unroll
    for (int o = 32; o >= 1; o >>= 1) sum += __shfl_xor(sum, o);
    float mu = sum * (1.0f / 256.0f);
    float d0 = v0 - mu, d1 = v1 - mu, d2 = v2 - mu, d3 = v3 - mu;
    float vs = d0 * d0 + d1 * d1 + d2 * d2 + d3 * d3;
#pragma unroll
    for (int o = 32; o >= 1; o >>= 1) vs += __shfl_xor(vs, o);
    float rstd = rsqrtf(vs * (1.0f / 256.0f) + LN_EPS);
    float4 gv = *reinterpret_cast<const float4*>(lng + lane * 4);
    float4 bb = *reinterpret_cast<const float4*>(lnb + lane * 4);
    float o0 = d0 * rstd * gv.x + bb.x;
    float o1 = d1 * rstd * gv.y + bb.y;
    float o2 = d2 * rstd * gv.z + bb.z;
    float o3 = d3 * rstd * gv.w + bb.w;
    // ELU
    o0 = (o0 > 0.f) ? o0 : (expf(o0) - 1.0f);
    o1 = (o1 > 0.f) ? o1 : (expf(o1) - 1.0f);
    o2 = (o2 > 0.f) ? o2 : (expf(o2) - 1.0f);
    o3 = (o3 > 0.f) ? o3 : (expf(o3) - 1.0f);
    *reinterpret_cast<float4*>(Y + (size_t)n * 256 + lane * 4) = make_float4(o0, o1, o2, o3);
}

// ---------------- layer 2: h2 = Y * W2 (256->1) ----------------

__global__ __launch_bounds__(256) void k_gemm2(
    const float* __restrict__ Y, const float* __restrict__ W2,
    float* __restrict__ h2, int N)
{
    const int wid = threadIdx.x >> 6;
    const int lane = threadIdx.x & 63;
    const int n = blockIdx.x * 4 + wid;
    if (n >= N) return;
    float4 yv = *reinterpret_cast<const float4*>(Y + (size_t)n * 256 + lane * 4);
    float4 wv = *reinterpret_cast<const float4*>(W2 + lane * 4);
    float p = yv.x * wv.x + yv.y * wv.y + yv.z * wv.z + yv.w * wv.w;
#pragma unroll
    for (int o = 32; o >= 1; o >>= 1) p += __shfl_xor(p, o);
    if (lane == 0) h2[n] = p;
}

// ---------------- layer 2 aggregation (H=1, C=1) ----------------

__global__ __launch_bounds__(256) void k_agg2(
    const int* __restrict__ offs, const int* __restrict__ csr,
    const float* __restrict__ h2,
    const float* __restrict__ as2, const float* __restrict__ ad2,
    const float* __restrict__ b2, float* __restrict__ out, int N)
{
    const int wid = threadIdx.x >> 6;
    const int lane = threadIdx.x & 63;
    const int n = blockIdx.x * 4 + wid;
    if (n >= N) return;
    const float asv = as2[0], adv = ad2[0];
    const float tval = adv * h2[n];
    const int beg = offs[n], end = offs[n + 1];

    float m = -1e30f;
    for (int i = beg + lane; i < end; i += 64) {
        float e = asv * h2[csr[i]] + tval;
        e = (e > 0.f) ? e : NEG_SLOPE * e;
        m = fmaxf(m, e);
    }
#pragma unroll
    for (int o = 32; o >= 1; o >>= 1) m = fmaxf(m, __shfl_xor(m, o));
    float den = 0.f, num = 0.f;
    for (int i = beg + lane; i < end; i += 64) {
        float hv = h2[csr[i]];
        float e = asv * hv + tval;
        e = (e > 0.f) ? e : NEG_SLOPE * e;
        float p = __expf(e - m);
        den += p;
        num = fmaf(p, hv, num);
    }
#pragma unroll
    for (int o = 32; o >= 1; o >>= 1) { den += __shfl_xor(den, o); num += __shfl_xor(num, o); }
    if (lane == 0) out[n] = num / den + b2[0];
}

// ---------------- launch ----------------

extern "C" void kernel_launch(void* const* d_in, const int* in_sizes, int n_in,
                              void* d_out, int out_size, void* d_ws, size_t ws_size,
                              hipStream_t stream) {
    const float* x   = (const float*)d_in[0];
    const int*   ei  = (const int*)d_in[1];
    const float* W0  = (const float*)d_in[2];
    const float* as0 = (const float*)d_in[3];
    const float* ad0 = (const float*)d_in[4];
    const float* b0  = (const float*)d_in[5];
    const float* W1  = (const float*)d_in[6];
    const float* as1 = (const float*)d_in[7];
    const float* ad1 = (const float*)d_in[8];
    const float* b1  = (const float*)d_in[9];
    const float* W2  = (const float*)d_in[10];
    const float* as2 = (const float*)d_in[11];
    const float* ad2 = (const float*)d_in[12];
    const float* b2  = (const float*)d_in[13];
    const float* lng = (const float*)d_in[14];
    const float* lnb = (const float*)d_in[15];

    const int N = in_sizes[0] / 64;
    const int E = in_sizes[1] / 2;
    const int TOT = E + N;

    char* w = (char*)d_ws;
    auto alloc = [&](size_t bytes) -> void* {
        void* p = (void*)w;
        w += (bytes + 255) & ~(size_t)255;
        return p;
    };
    int*   cnt    = (int*)alloc(sizeof(int) * N);
    int*   offs   = (int*)alloc(sizeof(int) * (N + 1));
    int*   cursor = (int*)alloc(sizeof(int) * N);
    int*   csr    = (int*)alloc(sizeof(int) * TOT);
    float* sbuf   = (float*)alloc(sizeof(float) * N * 4);
    float* tbuf   = (float*)alloc(sizeof(float) * N * 4);
    float* h      = (float*)alloc(sizeof(float) * (size_t)N * 256);
    float* Y      = (float*)alloc(sizeof(float) * (size_t)N * 256);
    float* h2     = (float*)alloc(sizeof(float) * N);
    float* out    = (float*)d_out;

    // CSR build
    k_zero<<<(N + 255) / 256, 256, 0, stream>>>(cnt, N);
    k_hist<<<(TOT + 255) / 256, 256, 0, stream>>>(ei, E, N, cnt);
    k_scan<<<1, 1024, 0, stream>>>(cnt, offs, N);
    k_copy<<<(N + 255) / 256, 256, 0, stream>>>(offs, cursor, N);
    k_scatter<<<(TOT + 255) / 256, 256, 0, stream>>>(ei, E, N, cursor, csr);

    const int gemm_grid = (N + 63) / 64;
    const int node_grid = (N + 3) / 4;

    // layer 0
    k_gemm_st<64><<<gemm_grid, 256, 0, stream>>>(x, W0, as0, ad0, h, sbuf, tbuf, N);
    k_agg_ln_elu<<<node_grid, 256, 0, stream>>>(offs, csr, sbuf, tbuf, h, b0, lng, lnb, Y, N);
    // layer 1
    k_gemm_st<256><<<gemm_grid, 256, 0, stream>>>(Y, W1, as1, ad1, h, sbuf, tbuf, N);
    k_agg_ln_elu<<<node_grid, 256, 0, stream>>>(offs, csr, sbuf, tbuf, h, b1, lng, lnb, Y, N);
    // layer 2
    k_gemm2<<<node_grid, 256, 0, stream>>>(Y, W2, h2, N);
    k_agg2<<<node_grid, 256, 0, stream>>>(offs, csr, h2, as2, ad2, b2, out, N);
}

// Round 2
// 693.324 us; speedup vs baseline: 1.1093x; 1.1093x over previous
//
#include <hip/hip_runtime.h>
#include <math.h>

constexpr float NEG_SLOPE = 0.2f;
constexpr float LN_EPS = 1e-5f;

// ---------------- CSR build ----------------

__global__ void k_zero(int* __restrict__ p, int n) {
    int i = blockIdx.x * blockDim.x + threadIdx.x;
    if (i < n) p[i] = 0;
}

__global__ void k_hist(const int* __restrict__ ei, int E, int N, int* __restrict__ cnt) {
    int i = blockIdx.x * blockDim.x + threadIdx.x;
    if (i >= E + N) return;
    int dst = (i < E) ? ei[E + i] : (i - E);
    atomicAdd(&cnt[dst], 1);
}

// single-block scan, wave-shuffle based: offs[0]=0, offs[i+1]=sum(cnt[0..i])
__global__ __launch_bounds__(1024) void k_scan(const int* __restrict__ cnt,
                                               int* __restrict__ offs, int n) {
    __shared__ int wsum[16];
    __shared__ int carry_s;
    const int lane = threadIdx.x & 63;
    const int w = threadIdx.x >> 6;
    if (threadIdx.x == 0) { carry_s = 0; offs[0] = 0; }
    __syncthreads();
    for (int base = 0; base < n; base += 1024) {
        int i = base + (int)threadIdx.x;
        int sv = (i < n) ? cnt[i] : 0;
#pragma unroll
        for (int off = 1; off < 64; off <<= 1) {
            int u = __shfl_up(sv, off);
            if (lane >= off) sv += u;
        }
        if (lane == 63) wsum[w] = sv;
        __syncthreads();
        if (w == 0) {
            int x = (lane < 16) ? wsum[lane] : 0;
#pragma unroll
            for (int off = 1; off < 16; off <<= 1) {
                int u = __shfl_up(x, off);
                if (lane >= off) x += u;
            }
            if (lane < 16) wsum[lane] = x;  // inclusive wave-prefix
        }
        __syncthreads();
        int wbase = (w == 0) ? 0 : wsum[w - 1];
        if (i < n) offs[i + 1] = carry_s + wbase + sv;
        __syncthreads();
        if (threadIdx.x == 0) carry_s += wsum[15];
        __syncthreads();
    }
}

__global__ void k_copy(const int* __restrict__ a, int* __restrict__ b, int n) {
    int i = blockIdx.x * blockDim.x + threadIdx.x;
    if (i < n) b[i] = a[i];
}

__global__ void k_scatter(const int* __restrict__ ei, int E, int N,
                          int* __restrict__ cursor, int* __restrict__ csr) {
    int i = blockIdx.x * blockDim.x + threadIdx.x;
    if (i >= E + N) return;
    int src, dst;
    if (i < E) { src = ei[i]; dst = ei[E + i]; }
    else       { src = i - E; dst = i - E; }
    int pos = atomicAdd(&cursor[dst], 1);
    csr[pos] = src;
}

// ---------------- GEMM h = X * W  (+ fused s,t scores) ----------------
// X: [N,K], W: [K,256], h: [N,256], s,t: [N,4]
// block = 256 threads; tile = 64 rows x 256 cols; thread = 8 rows x
// cols {4tc..4tc+3, 128+4tc..128+4tc+3}. W staged in LDS 32-k chunks
// (conflict-free contiguous-16B reads); X read directly from global
// (broadcast within 16-lane groups, L1-resident column working set).

template <int K>
__global__ __launch_bounds__(256, 4) void k_gemm_st(
    const float* __restrict__ X, const float* __restrict__ W,
    const float* __restrict__ a_s, const float* __restrict__ a_d,
    float* __restrict__ h, float* __restrict__ s, float* __restrict__ t, int N)
{
    __shared__ float Wl[32][256];   // 32 KB

    const int tid = threadIdx.x;
    const int row0 = blockIdx.x * 64;
    const int tc = tid & 31;   // col group
    const int tr = tid >> 5;   // row group: rows 8*tr .. 8*tr+7

    const float* xp[8];
#pragma unroll
    for (int i = 0; i < 8; ++i) {
        int row = row0 + 8 * tr + i;
        row = (row < N) ? row : (N - 1);    // clamp; OOB rows never written
        xp[i] = X + (size_t)row * K;
    }

    float acc[8][8];
#pragma unroll
    for (int i = 0; i < 8; ++i)
#pragma unroll
        for (int j = 0; j < 8; ++j) acc[i][j] = 0.0f;

    for (int k0 = 0; k0 < K; k0 += 32) {
        __syncthreads();
        // stage W chunk: 32x256 floats = 2048 float4 / 256 thr = 8 each
#pragma unroll
        for (int it = 0; it < 8; ++it) {
            int idx = tid + it * 256;
            int kk = idx >> 6;
            int c4 = idx & 63;
            *reinterpret_cast<float4*>(&Wl[kk][c4 * 4]) =
                *reinterpret_cast<const float4*>(W + (size_t)(k0 + kk) * 256 + c4 * 4);
        }
        __syncthreads();
#pragma unroll 2
        for (int kk = 0; kk < 32; ++kk) {
            float4 wa = *reinterpret_cast<const float4*>(&Wl[kk][4 * tc]);
            float4 wb = *reinterpret_cast<const float4*>(&Wl[kk][128 + 4 * tc]);
            float xr[8];
#pragma unroll
            for (int i = 0; i < 8; ++i) xr[i] = xp[i][k0 + kk];
            float wc[8] = {wa.x, wa.y, wa.z, wa.w, wb.x, wb.y, wb.z, wb.w};
#pragma unroll
            for (int i = 0; i < 8; ++i)
#pragma unroll
                for (int j = 0; j < 8; ++j)
                    acc[i][j] = fmaf(xr[i], wc[j], acc[i][j]);
        }
    }

    // epilogue: write h, fused s,t
    float4 asa = *reinterpret_cast<const float4*>(a_s + 4 * tc);
    float4 asb = *reinterpret_cast<const float4*>(a_s + 128 + 4 * tc);
    float4 ada = *reinterpret_cast<const float4*>(a_d + 4 * tc);
    float4 adb = *reinterpret_cast<const float4*>(a_d + 128 + 4 * tc);
    float asv[8] = {asa.x, asa.y, asa.z, asa.w, asb.x, asb.y, asb.z, asb.w};
    float adv[8] = {ada.x, ada.y, ada.z, ada.w, adb.x, adb.y, adb.z, adb.w};
    const int hA = tc >> 4;        // head of cols 4tc..4tc+3 (0 or 1)
    const int hB = 2 + (tc >> 4);  // head of cols 128+4tc.. (2 or 3)

#pragma unroll
    for (int i = 0; i < 8; ++i) {
        int row = row0 + 8 * tr + i;
        if (row < N) {
            float4 o0 = make_float4(acc[i][0], acc[i][1], acc[i][2], acc[i][3]);
            float4 o1 = make_float4(acc[i][4], acc[i][5], acc[i][6], acc[i][7]);
            *reinterpret_cast<float4*>(h + (size_t)row * 256 + 4 * tc) = o0;
            *reinterpret_cast<float4*>(h + (size_t)row * 256 + 128 + 4 * tc) = o1;
            float psA = 0.f, ptA = 0.f, psB = 0.f, ptB = 0.f;
#pragma unroll
            for (int j = 0; j < 4; ++j) {
                psA = fmaf(acc[i][j], asv[j], psA);
                ptA = fmaf(acc[i][j], adv[j], ptA);
                psB = fmaf(acc[i][4 + j], asv[4 + j], psB);
                ptB = fmaf(acc[i][4 + j], adv[4 + j], ptB);
            }
            // reduce across the 16 lanes sharing a head (tc&15)
            psA += __shfl_xor(psA, 1); psA += __shfl_xor(psA, 2);
            psA += __shfl_xor(psA, 4); psA += __shfl_xor(psA, 8);
            ptA += __shfl_xor(ptA, 1); ptA += __shfl_xor(ptA, 2);
            ptA += __shfl_xor(ptA, 4); ptA += __shfl_xor(ptA, 8);
            psB += __shfl_xor(psB, 1); psB += __shfl_xor(psB, 2);
            psB += __shfl_xor(psB, 4); psB += __shfl_xor(psB, 8);
            ptB += __shfl_xor(ptB, 1); ptB += __shfl_xor(ptB, 2);
            ptB += __shfl_xor(ptB, 4); ptB += __shfl_xor(ptB, 8);
            if ((tc & 15) == 0) {
                s[(size_t)row * 4 + hA] = psA;
                t[(size_t)row * 4 + hA] = ptA;
                s[(size_t)row * 4 + hB] = psB;
                t[(size_t)row * 4 + hB] = ptB;
            }
        }
    }
}

// ---------------- aggregation (+ bias + LayerNorm + ELU) ----------------
// one wave per destination node; lane owns 4 channels; head = lane>>4

__global__ __launch_bounds__(256) void k_agg_ln_elu(
    const int* __restrict__ offs, const int* __restrict__ csr,
    const float* __restrict__ s, const float* __restrict__ t,
    const float* __restrict__ h, const float* __restrict__ bias,
    const float* __restrict__ lng, const float* __restrict__ lnb,
    float* __restrict__ Y, int N)
{
    const int wid = threadIdx.x >> 6;
    const int lane = threadIdx.x & 63;
    const int n = blockIdx.x * 4 + wid;
    if (n >= N) return;
    const int head = lane >> 4;
    const float tval = t[(size_t)n * 4 + head];
    const int beg = offs[n], end = offs[n + 1];

    float m = -1e30f;
    for (int i = beg; i < end; ++i) {
        int src = csr[i];
        float e = s[(size_t)src * 4 + head] + tval;
        e = (e > 0.f) ? e : NEG_SLOPE * e;
        m = fmaxf(m, e);
    }
    float den = 0.f;
    float4 acc = make_float4(0.f, 0.f, 0.f, 0.f);
    for (int i = beg; i < end; ++i) {
        int src = csr[i];
        float e = s[(size_t)src * 4 + head] + tval;
        e = (e > 0.f) ? e : NEG_SLOPE * e;
        float p = __expf(e - m);
        den += p;
        float4 hv = *reinterpret_cast<const float4*>(h + (size_t)src * 256 + lane * 4);
        acc.x = fmaf(p, hv.x, acc.x);
        acc.y = fmaf(p, hv.y, acc.y);
        acc.z = fmaf(p, hv.z, acc.z);
        acc.w = fmaf(p, hv.w, acc.w);
    }
    const float inv = 1.0f / den;
    float4 bv = *reinterpret_cast<const float4*>(bias + lane * 4);
    float v0 = acc.x * inv + bv.x;
    float v1 = acc.y * inv + bv.y;
    float v2 = acc.z * inv + bv.z;
    float v3 = acc.w * inv + bv.w;

    // LayerNorm over 256 features (held by this wave)
    float sum = v0 + v1 + v2 + v3;
#pragma unroll
    for (int o = 32; o >= 1; o >>= 1) sum += __shfl_xor(sum, o);
    float mu = sum * (1.0f / 256.0f);
    float d0 = v0 - mu, d1 = v1 - mu, d2 = v2 - mu, d3 = v3 - mu;
    float vs = d0 * d0 + d1 * d1 + d2 * d2 + d3 * d3;
#pragma unroll
    for (int o = 32; o >= 1; o >>= 1) vs += __shfl_xor(vs, o);
    float rstd = rsqrtf(vs * (1.0f / 256.0f) + LN_EPS);
    float4 gv = *reinterpret_cast<const float4*>(lng + lane * 4);
    float4 bb = *reinterpret_cast<const float4*>(lnb + lane * 4);
    float o0 = d0 * rstd * gv.x + bb.x;
    float o1 = d1 * rstd * gv.y + bb.y;
    float o2 = d2 * rstd * gv.z + bb.z;
    float o3 = d3 * rstd * gv.w + bb.w;
    // ELU
    o0 = (o0 > 0.f) ? o0 : (expf(o0) - 1.0f);
    o1 = (o1 > 0.f) ? o1 : (expf(o1) - 1.0f);
    o2 = (o2 > 0.f) ? o2 : (expf(o2) - 1.0f);
    o3 = (o3 > 0.f) ? o3 : (expf(o3) - 1.0f);
    *reinterpret_cast<float4*>(Y + (size_t)n * 256 + lane * 4) = make_float4(o0, o1, o2, o3);
}

// ---------------- layer 2: h2 = Y * W2 (256->1) ----------------

__global__ __launch_bounds__(256) void k_gemm2(
    const float* __restrict__ Y, const float* __restrict__ W2,
    float* __restrict__ h2, int N)
{
    const int wid = threadIdx.x >> 6;
    const int lane = threadIdx.x & 63;
    const int n = blockIdx.x * 4 + wid;
    if (n >= N) return;
    float4 yv = *reinterpret_cast<const float4*>(Y + (size_t)n * 256 + lane * 4);
    float4 wv = *reinterpret_cast<const float4*>(W2 + lane * 4);
    float p = yv.x * wv.x + yv.y * wv.y + yv.z * wv.z + yv.w * wv.w;
#pragma unroll
    for (int o = 32; o >= 1; o >>= 1) p += __shfl_xor(p, o);
    if (lane == 0) h2[n] = p;
}

// ---------------- layer 2 aggregation (H=1, C=1) ----------------

__global__ __launch_bounds__(256) void k_agg2(
    const int* __restrict__ offs, const int* __restrict__ csr,
    const float* __restrict__ h2,
    const float* __restrict__ as2, const float* __restrict__ ad2,
    const float* __restrict__ b2, float* __restrict__ out, int N)
{
    const int wid = threadIdx.x >> 6;
    const int lane = threadIdx.x & 63;
    const int n = blockIdx.x * 4 + wid;
    if (n >= N) return;
    const float asv = as2[0], adv = ad2[0];
    const float tval = adv * h2[n];
    const int beg = offs[n], end = offs[n + 1];

    float m = -1e30f;
    for (int i = beg + lane; i < end; i += 64) {
        float e = asv * h2[csr[i]] + tval;
        e = (e > 0.f) ? e : NEG_SLOPE * e;
        m = fmaxf(m, e);
    }
#pragma unroll
    for (int o = 32; o >= 1; o >>= 1) m = fmaxf(m, __shfl_xor(m, o));
    float den = 0.f, num = 0.f;
    for (int i = beg + lane; i < end; i += 64) {
        float hv = h2[csr[i]];
        float e = asv * hv + tval;
        e = (e > 0.f) ? e : NEG_SLOPE * e;
        float p = __expf(e - m);
        den += p;
        num = fmaf(p, hv, num);
    }
#pragma unroll
    for (int o = 32; o >= 1; o >>= 1) { den += __shfl_xor(den, o); num += __shfl_xor(num, o); }
    if (lane == 0) out[n] = num / den + b2[0];
}

// ---------------- launch ----------------

extern "C" void kernel_launch(void* const* d_in, const int* in_sizes, int n_in,
                              void* d_out, int out_size, void* d_ws, size_t ws_size,
                              hipStream_t stream) {
    const float* x   = (const float*)d_in[0];
    const int*   ei  = (const int*)d_in[1];
    const float* W0  = (const float*)d_in[2];
    const float* as0 = (const float*)d_in[3];
    const float* ad0 = (const float*)d_in[4];
    const float* b0  = (const float*)d_in[5];
    const float* W1  = (const float*)d_in[6];
    const float* as1 = (const float*)d_in[7];
    const float* ad1 = (const float*)d_in[8];
    const float* b1  = (const float*)d_in[9];
    const float* W2  = (const float*)d_in[10];
    const float* as2 = (const float*)d_in[11];
    const float* ad2 = (const float*)d_in[12];
    const float* b2  = (const float*)d_in[13];
    const float* lng = (const float*)d_in[14];
    const float* lnb = (const float*)d_in[15];

    const int N = in_sizes[0] / 64;
    const int E = in_sizes[1] / 2;
    const int TOT = E + N;

    char* w = (char*)d_ws;
    auto alloc = [&](size_t bytes) -> void* {
        void* p = (void*)w;
        w += (bytes + 255) & ~(size_t)255;
        return p;
    };
    int*   cnt    = (int*)alloc(sizeof(int) * N);
    int*   offs   = (int*)alloc(sizeof(int) * (N + 1));
    int*   cursor = (int*)alloc(sizeof(int) * N);
    int*   csr    = (int*)alloc(sizeof(int) * TOT);
    float* sbuf   = (float*)alloc(sizeof(float) * N * 4);
    float* tbuf   = (float*)alloc(sizeof(float) * N * 4);
    float* h      = (float*)alloc(sizeof(float) * (size_t)N * 256);
    float* Y      = (float*)alloc(sizeof(float) * (size_t)N * 256);
    float* h2     = (float*)alloc(sizeof(float) * N);
    float* out    = (float*)d_out;

    // CSR build
    k_zero<<<(N + 255) / 256, 256, 0, stream>>>(cnt, N);
    k_hist<<<(TOT + 255) / 256, 256, 0, stream>>>(ei, E, N, cnt);
    k_scan<<<1, 1024, 0, stream>>>(cnt, offs, N);
    k_copy<<<(N + 255) / 256, 256, 0, stream>>>(offs, cursor, N);
    k_scatter<<<(TOT + 255) / 256, 256, 0, stream>>>(ei, E, N, cursor, csr);

    const int gemm_grid = (N + 63) / 64;
    const int node_grid = (N + 3) / 4;

    // layer 0
    k_gemm_st<64><<<gemm_grid, 256, 0, stream>>>(x, W0, as0, ad0, h, sbuf, tbuf, N);
    k_agg_ln_elu<<<node_grid, 256, 0, stream>>>(offs, csr, sbuf, tbuf, h, b0, lng, lnb, Y, N);
    // layer 1
    k_gemm_st<256><<<gemm_grid, 256, 0, stream>>>(Y, W1, as1, ad1, h, sbuf, tbuf, N);
    k_agg_ln_elu<<<node_grid, 256, 0, stream>>>(offs, csr, sbuf, tbuf, h, b1, lng, lnb, Y, N);
    // layer 2
    k_gemm2<<<node_grid, 256, 0, stream>>>(Y, W2, h2, N);
    k_agg2<<<node_grid, 256, 0, stream>>>(offs, csr, h2, as2, ad2, b2, out, N);
}

// Round 3
// 583.470 us; speedup vs baseline: 1.3181x; 1.1883x over previous
//
#include <hip/hip_runtime.h>
#include <math.h>

constexpr float NEG_SLOPE = 0.2f;
constexpr float LN_EPS = 1e-5f;

// ---------------- small helpers ----------------

__device__ inline float4 wave_max4(float4 v) {
#pragma unroll
    for (int off = 1; off < 64; off <<= 1) {
        v.x = fmaxf(v.x, __shfl_xor(v.x, off));
        v.y = fmaxf(v.y, __shfl_xor(v.y, off));
        v.z = fmaxf(v.z, __shfl_xor(v.z, off));
        v.w = fmaxf(v.w, __shfl_xor(v.w, off));
    }
    return v;
}

__device__ inline float4 wave_sum4(float4 v) {
#pragma unroll
    for (int off = 1; off < 64; off <<= 1) {
        v.x += __shfl_xor(v.x, off);
        v.y += __shfl_xor(v.y, off);
        v.z += __shfl_xor(v.z, off);
        v.w += __shfl_xor(v.w, off);
    }
    return v;
}

__device__ inline float pick4(float4 v, int h) {
    float r = v.x;
    r = (h == 1) ? v.y : r;
    r = (h == 2) ? v.z : r;
    r = (h == 3) ? v.w : r;
    return r;
}

// ---------------- CSR build ----------------

__global__ void k_zero(int* __restrict__ p, int n) {
    int i = blockIdx.x * blockDim.x + threadIdx.x;
    if (i < n) p[i] = 0;
}

__global__ void k_hist(const int* __restrict__ ei, int E, int N, int* __restrict__ cnt) {
    int i = blockIdx.x * blockDim.x + threadIdx.x;
    if (i >= E + N) return;
    int dst = (i < E) ? ei[E + i] : (i - E);
    atomicAdd(&cnt[dst], 1);
}

// hierarchical scan: offs[0]=0, offs[i+1]=sum(cnt[0..i])
__global__ __launch_bounds__(1024) void k_scan1(const int* __restrict__ cnt,
                                                int* __restrict__ offs,
                                                int* __restrict__ bsum, int n) {
    __shared__ int wsum[16];
    const int lane = threadIdx.x & 63;
    const int w = threadIdx.x >> 6;
    int i = blockIdx.x * 1024 + threadIdx.x;
    int v = (i < n) ? cnt[i] : 0;
#pragma unroll
    for (int off = 1; off < 64; off <<= 1) {
        int u = __shfl_up(v, off);
        if (lane >= off) v += u;
    }
    if (lane == 63) wsum[w] = v;
    __syncthreads();
    if (w == 0) {
        int x = (lane < 16) ? wsum[lane] : 0;
#pragma unroll
        for (int off = 1; off < 16; off <<= 1) {
            int u = __shfl_up(x, off);
            if (lane >= off) x += u;
        }
        if (lane < 16) wsum[lane] = x;
    }
    __syncthreads();
    v += (w > 0) ? wsum[w - 1] : 0;
    if (i < n) offs[i + 1] = v;
    if (threadIdx.x == 1023) bsum[blockIdx.x] = v;
}

// exclusive scan of block sums (nb <= 1024), in place -> bcarry
__global__ __launch_bounds__(1024) void k_scan2(const int* __restrict__ bsum,
                                                int* __restrict__ bcarry, int nb) {
    __shared__ int wsum[16];
    const int lane = threadIdx.x & 63;
    const int w = threadIdx.x >> 6;
    int v0 = ((int)threadIdx.x < nb) ? bsum[threadIdx.x] : 0;
    int v = v0;
#pragma unroll
    for (int off = 1; off < 64; off <<= 1) {
        int u = __shfl_up(v, off);
        if (lane >= off) v += u;
    }
    if (lane == 63) wsum[w] = v;
    __syncthreads();
    if (w == 0) {
        int x = (lane < 16) ? wsum[lane] : 0;
#pragma unroll
        for (int off = 1; off < 16; off <<= 1) {
            int u = __shfl_up(x, off);
            if (lane >= off) x += u;
        }
        if (lane < 16) wsum[lane] = x;
    }
    __syncthreads();
    v += (w > 0) ? wsum[w - 1] : 0;
    if ((int)threadIdx.x < nb) bcarry[threadIdx.x] = v - v0;  // exclusive
}

__global__ void k_scan3(int* __restrict__ offs, const int* __restrict__ bcarry,
                        int* __restrict__ cursor, int n) {
    int i = blockIdx.x * blockDim.x + threadIdx.x;
    if (i == 0) offs[0] = 0;
    if (i < n) {
        int v = offs[i + 1] + bcarry[i >> 10];
        offs[i + 1] = v;
    }
}

__global__ void k_copy(const int* __restrict__ a, int* __restrict__ b, int n) {
    int i = blockIdx.x * blockDim.x + threadIdx.x;
    if (i < n) b[i] = a[i];
}

__global__ void k_scatter(const int* __restrict__ ei, int E, int N,
                          int* __restrict__ cursor, int* __restrict__ csr) {
    int i = blockIdx.x * blockDim.x + threadIdx.x;
    if (i >= E + N) return;
    int src, dst;
    if (i < E) { src = ei[i]; dst = ei[E + i]; }
    else       { src = i - E; dst = i - E; }
    int pos = atomicAdd(&cursor[dst], 1);
    csr[pos] = src;
}

// ---------------- GEMM h = X * W  (+ fused s,t scores) ----------------

template <int K>
__global__ __launch_bounds__(256, 4) void k_gemm_st(
    const float* __restrict__ X, const float* __restrict__ W,
    const float* __restrict__ a_s, const float* __restrict__ a_d,
    float* __restrict__ h, float* __restrict__ s, float* __restrict__ t, int N)
{
    __shared__ float Wl[32][256];   // 32 KB

    const int tid = threadIdx.x;
    const int row0 = blockIdx.x * 64;
    const int tc = tid & 31;
    const int tr = tid >> 5;

    const float* xp[8];
#pragma unroll
    for (int i = 0; i < 8; ++i) {
        int row = row0 + 8 * tr + i;
        row = (row < N) ? row : (N - 1);
        xp[i] = X + (size_t)row * K;
    }

    float acc[8][8];
#pragma unroll
    for (int i = 0; i < 8; ++i)
#pragma unroll
        for (int j = 0; j < 8; ++j) acc[i][j] = 0.0f;

    for (int k0 = 0; k0 < K; k0 += 32) {
        __syncthreads();
#pragma unroll
        for (int it = 0; it < 8; ++it) {
            int idx = tid + it * 256;
            int kk = idx >> 6;
            int c4 = idx & 63;
            *reinterpret_cast<float4*>(&Wl[kk][c4 * 4]) =
                *reinterpret_cast<const float4*>(W + (size_t)(k0 + kk) * 256 + c4 * 4);
        }
        __syncthreads();
#pragma unroll 2
        for (int kk = 0; kk < 32; ++kk) {
            float4 wa = *reinterpret_cast<const float4*>(&Wl[kk][4 * tc]);
            float4 wb = *reinterpret_cast<const float4*>(&Wl[kk][128 + 4 * tc]);
            float xr[8];
#pragma unroll
            for (int i = 0; i < 8; ++i) xr[i] = xp[i][k0 + kk];
            float wc[8] = {wa.x, wa.y, wa.z, wa.w, wb.x, wb.y, wb.z, wb.w};
#pragma unroll
            for (int i = 0; i < 8; ++i)
#pragma unroll
                for (int j = 0; j < 8; ++j)
                    acc[i][j] = fmaf(xr[i], wc[j], acc[i][j]);
        }
    }

    float4 asa = *reinterpret_cast<const float4*>(a_s + 4 * tc);
    float4 asb = *reinterpret_cast<const float4*>(a_s + 128 + 4 * tc);
    float4 ada = *reinterpret_cast<const float4*>(a_d + 4 * tc);
    float4 adb = *reinterpret_cast<const float4*>(a_d + 128 + 4 * tc);
    float asv[8] = {asa.x, asa.y, asa.z, asa.w, asb.x, asb.y, asb.z, asb.w};
    float adv[8] = {ada.x, ada.y, ada.z, ada.w, adb.x, adb.y, adb.z, adb.w};
    const int hA = tc >> 4;
    const int hB = 2 + (tc >> 4);

#pragma unroll
    for (int i = 0; i < 8; ++i) {
        int row = row0 + 8 * tr + i;
        if (row < N) {
            float4 o0 = make_float4(acc[i][0], acc[i][1], acc[i][2], acc[i][3]);
            float4 o1 = make_float4(acc[i][4], acc[i][5], acc[i][6], acc[i][7]);
            *reinterpret_cast<float4*>(h + (size_t)row * 256 + 4 * tc) = o0;
            *reinterpret_cast<float4*>(h + (size_t)row * 256 + 128 + 4 * tc) = o1;
            float psA = 0.f, ptA = 0.f, psB = 0.f, ptB = 0.f;
#pragma unroll
            for (int j = 0; j < 4; ++j) {
                psA = fmaf(acc[i][j], asv[j], psA);
                ptA = fmaf(acc[i][j], adv[j], ptA);
                psB = fmaf(acc[i][4 + j], asv[4 + j], psB);
                ptB = fmaf(acc[i][4 + j], adv[4 + j], ptB);
            }
            psA += __shfl_xor(psA, 1); psA += __shfl_xor(psA, 2);
            psA += __shfl_xor(psA, 4); psA += __shfl_xor(psA, 8);
            ptA += __shfl_xor(ptA, 1); ptA += __shfl_xor(ptA, 2);
            ptA += __shfl_xor(ptA, 4); ptA += __shfl_xor(ptA, 8);
            psB += __shfl_xor(psB, 1); psB += __shfl_xor(psB, 2);
            psB += __shfl_xor(psB, 4); psB += __shfl_xor(psB, 8);
            ptB += __shfl_xor(ptB, 1); ptB += __shfl_xor(ptB, 2);
            ptB += __shfl_xor(ptB, 4); ptB += __shfl_xor(ptB, 8);
            if ((tc & 15) == 0) {
                s[(size_t)row * 4 + hA] = psA;
                t[(size_t)row * 4 + hA] = ptA;
                s[(size_t)row * 4 + hB] = psB;
                t[(size_t)row * 4 + hB] = ptB;
            }
        }
    }
}

// ---------------- aggregation (+ bias + LayerNorm + ELU) ----------------
// one wave per destination node; lane owns 4 channels; head = lane>>4.
// Single online-softmax pass: per 64-edge chunk, lane j owns edge (beg+j):
// coalesced csr load + 16B s-gather, wave-reduced per-head max, online
// rescale; p/src parked in LDS so the h-gather loop has no dependent loads.

__global__ __launch_bounds__(256) void k_agg_ln_elu(
    const int* __restrict__ offs, const int* __restrict__ csr,
    const float* __restrict__ s, const float* __restrict__ t,
    const float* __restrict__ h, const float* __restrict__ bias,
    const float* __restrict__ lng, const float* __restrict__ lnb,
    float* __restrict__ Y, int N)
{
    __shared__ float p_s[4][256];
    __shared__ int src_s[4][64];

    const int wid = threadIdx.x >> 6;
    const int lane = threadIdx.x & 63;
    const int n = blockIdx.x * 4 + wid;
    if (n >= N) return;
    const int head = lane >> 4;
    const float4 t4 = *reinterpret_cast<const float4*>(t + (size_t)n * 4);
    const int beg = offs[n], end = offs[n + 1];

    float4 m4 = make_float4(-1e30f, -1e30f, -1e30f, -1e30f);
    float4 den4 = make_float4(0.f, 0.f, 0.f, 0.f);
    float4 acc = make_float4(0.f, 0.f, 0.f, 0.f);

    for (int base = beg; base < end; base += 64) {
        const int cnt = min(64, end - base);
        const bool valid = lane < cnt;
        int src = 0;
        float4 e4 = make_float4(-1e30f, -1e30f, -1e30f, -1e30f);
        if (valid) {
            src = csr[base + lane];
            float4 sv = *reinterpret_cast<const float4*>(s + (size_t)src * 4);
            float ex = sv.x + t4.x, ey = sv.y + t4.y, ez = sv.z + t4.z, ew = sv.w + t4.w;
            e4.x = (ex > 0.f) ? ex : NEG_SLOPE * ex;
            e4.y = (ey > 0.f) ? ey : NEG_SLOPE * ey;
            e4.z = (ez > 0.f) ? ez : NEG_SLOPE * ez;
            e4.w = (ew > 0.f) ? ew : NEG_SLOPE * ew;
        }
        float4 bm = wave_max4(e4);
        float4 newm = make_float4(fmaxf(m4.x, bm.x), fmaxf(m4.y, bm.y),
                                  fmaxf(m4.z, bm.z), fmaxf(m4.w, bm.w));
        float4 sc4 = make_float4(__expf(m4.x - newm.x), __expf(m4.y - newm.y),
                                 __expf(m4.z - newm.z), __expf(m4.w - newm.w));
        m4 = newm;
        // rescale running sums
        float sch = pick4(sc4, head);
        acc.x *= sch; acc.y *= sch; acc.z *= sch; acc.w *= sch;
        float4 p4 = make_float4(__expf(e4.x - newm.x), __expf(e4.y - newm.y),
                                __expf(e4.z - newm.z), __expf(e4.w - newm.w));
        // (-1e30 - finite) underflows to 0 for invalid lanes
        den4.x = den4.x * sc4.x + p4.x;
        den4.y = den4.y * sc4.y + p4.y;
        den4.z = den4.z * sc4.z + p4.z;
        den4.w = den4.w * sc4.w + p4.w;

        *reinterpret_cast<float4*>(&p_s[wid][lane * 4]) = p4;
        src_s[wid][lane] = src;
        __builtin_amdgcn_s_waitcnt(0); // ds writes visible within wave

        const float* hb = h + (size_t)lane * 4;
#pragma unroll 4
        for (int jj = 0; jj < cnt; ++jj) {
            int srcj = src_s[wid][jj];
            float pj = p_s[wid][jj * 4 + head];
            float4 hv = *reinterpret_cast<const float4*>(hb + (size_t)srcj * 256);
            acc.x = fmaf(pj, hv.x, acc.x);
            acc.y = fmaf(pj, hv.y, acc.y);
            acc.z = fmaf(pj, hv.z, acc.z);
            acc.w = fmaf(pj, hv.w, acc.w);
        }
    }

    float4 dsum = wave_sum4(den4);
    const float inv = 1.0f / pick4(dsum, head);
    float4 bv = *reinterpret_cast<const float4*>(bias + lane * 4);
    float v0 = acc.x * inv + bv.x;
    float v1 = acc.y * inv + bv.y;
    float v2 = acc.z * inv + bv.z;
    float v3 = acc.w * inv + bv.w;

    float sum = v0 + v1 + v2 + v3;
#pragma unroll
    for (int o = 32; o >= 1; o >>= 1) sum += __shfl_xor(sum, o);
    float mu = sum * (1.0f / 256.0f);
    float d0 = v0 - mu, d1 = v1 - mu, d2 = v2 - mu, d3 = v3 - mu;
    float vs = d0 * d0 + d1 * d1 + d2 * d2 + d3 * d3;
#pragma unroll
    for (int o = 32; o >= 1; o >>= 1) vs += __shfl_xor(vs, o);
    float rstd = rsqrtf(vs * (1.0f / 256.0f) + LN_EPS);
    float4 gv = *reinterpret_cast<const float4*>(lng + lane * 4);
    float4 bb = *reinterpret_cast<const float4*>(lnb + lane * 4);
    float o0 = d0 * rstd * gv.x + bb.x;
    float o1 = d1 * rstd * gv.y + bb.y;
    float o2 = d2 * rstd * gv.z + bb.z;
    float o3 = d3 * rstd * gv.w + bb.w;
    o0 = (o0 > 0.f) ? o0 : (expf(o0) - 1.0f);
    o1 = (o1 > 0.f) ? o1 : (expf(o1) - 1.0f);
    o2 = (o2 > 0.f) ? o2 : (expf(o2) - 1.0f);
    o3 = (o3 > 0.f) ? o3 : (expf(o3) - 1.0f);
    *reinterpret_cast<float4*>(Y + (size_t)n * 256 + lane * 4) = make_float4(o0, o1, o2, o3);
}

// ---------------- layer 2: h2 = Y * W2 (256->1) ----------------

__global__ __launch_bounds__(256) void k_gemm2(
    const float* __restrict__ Y, const float* __restrict__ W2,
    float* __restrict__ h2, int N)
{
    const int wid = threadIdx.x >> 6;
    const int lane = threadIdx.x & 63;
    const int n = blockIdx.x * 4 + wid;
    if (n >= N) return;
    float4 yv = *reinterpret_cast<const float4*>(Y + (size_t)n * 256 + lane * 4);
    float4 wv = *reinterpret_cast<const float4*>(W2 + lane * 4);
    float p = yv.x * wv.x + yv.y * wv.y + yv.z * wv.z + yv.w * wv.w;
#pragma unroll
    for (int o = 32; o >= 1; o >>= 1) p += __shfl_xor(p, o);
    if (lane == 0) h2[n] = p;
}

// ---------------- layer 2 aggregation (H=1, C=1) ----------------

__global__ __launch_bounds__(256) void k_agg2(
    const int* __restrict__ offs, const int* __restrict__ csr,
    const float* __restrict__ h2,
    const float* __restrict__ as2, const float* __restrict__ ad2,
    const float* __restrict__ b2, float* __restrict__ out, int N)
{
    const int wid = threadIdx.x >> 6;
    const int lane = threadIdx.x & 63;
    const int n = blockIdx.x * 4 + wid;
    if (n >= N) return;
    const float asv = as2[0], adv = ad2[0];
    const float tval = adv * h2[n];
    const int beg = offs[n], end = offs[n + 1];

    float m = -1e30f;
    for (int i = beg + lane; i < end; i += 64) {
        float e = asv * h2[csr[i]] + tval;
        e = (e > 0.f) ? e : NEG_SLOPE * e;
        m = fmaxf(m, e);
    }
#pragma unroll
    for (int o = 32; o >= 1; o >>= 1) m = fmaxf(m, __shfl_xor(m, o));
    float den = 0.f, num = 0.f;
    for (int i = beg + lane; i < end; i += 64) {
        float hv = h2[csr[i]];
        float e = asv * hv + tval;
        e = (e > 0.f) ? e : NEG_SLOPE * e;
        float p = __expf(e - m);
        den += p;
        num = fmaf(p, hv, num);
    }
#pragma unroll
    for (int o = 32; o >= 1; o >>= 1) { den += __shfl_xor(den, o); num += __shfl_xor(num, o); }
    if (lane == 0) out[n] = num / den + b2[0];
}

// ---------------- launch ----------------

extern "C" void kernel_launch(void* const* d_in, const int* in_sizes, int n_in,
                              void* d_out, int out_size, void* d_ws, size_t ws_size,
                              hipStream_t stream) {
    const float* x   = (const float*)d_in[0];
    const int*   ei  = (const int*)d_in[1];
    const float* W0  = (const float*)d_in[2];
    const float* as0 = (const float*)d_in[3];
    const float* ad0 = (const float*)d_in[4];
    const float* b0  = (const float*)d_in[5];
    const float* W1  = (const float*)d_in[6];
    const float* as1 = (const float*)d_in[7];
    const float* ad1 = (const float*)d_in[8];
    const float* b1  = (const float*)d_in[9];
    const float* W2  = (const float*)d_in[10];
    const float* as2 = (const float*)d_in[11];
    const float* ad2 = (const float*)d_in[12];
    const float* b2  = (const float*)d_in[13];
    const float* lng = (const float*)d_in[14];
    const float* lnb = (const float*)d_in[15];

    const int N = in_sizes[0] / 64;
    const int E = in_sizes[1] / 2;
    const int TOT = E + N;
    const int NB = (N + 1023) / 1024;

    char* w = (char*)d_ws;
    auto alloc = [&](size_t bytes) -> void* {
        void* p = (void*)w;
        w += (bytes + 255) & ~(size_t)255;
        return p;
    };
    int*   cnt    = (int*)alloc(sizeof(int) * N);
    int*   offs   = (int*)alloc(sizeof(int) * (N + 1));
    int*   cursor = (int*)alloc(sizeof(int) * N);
    int*   csr    = (int*)alloc(sizeof(int) * TOT);
    int*   bsum   = (int*)alloc(sizeof(int) * (NB + 1));
    int*   bcarry = (int*)alloc(sizeof(int) * (NB + 1));
    float* sbuf   = (float*)alloc(sizeof(float) * N * 4);
    float* tbuf   = (float*)alloc(sizeof(float) * N * 4);
    float* h      = (float*)alloc(sizeof(float) * (size_t)N * 256);
    float* Y      = (float*)alloc(sizeof(float) * (size_t)N * 256);
    float* h2     = (float*)alloc(sizeof(float) * N);
    float* out    = (float*)d_out;

    // CSR build
    k_zero<<<(N + 255) / 256, 256, 0, stream>>>(cnt, N);
    k_hist<<<(TOT + 255) / 256, 256, 0, stream>>>(ei, E, N, cnt);
    k_scan1<<<NB, 1024, 0, stream>>>(cnt, offs, bsum, N);
    k_scan2<<<1, 1024, 0, stream>>>(bsum, bcarry, NB);
    k_scan3<<<(N + 255) / 256, 256, 0, stream>>>(offs, bcarry, cursor, N);
    k_copy<<<(N + 255) / 256, 256, 0, stream>>>(offs, cursor, N);
    k_scatter<<<(TOT + 255) / 256, 256, 0, stream>>>(ei, E, N, cursor, csr);

    const int gemm_grid = (N + 63) / 64;
    const int node_grid = (N + 3) / 4;

    // layer 0
    k_gemm_st<64><<<gemm_grid, 256, 0, stream>>>(x, W0, as0, ad0, h, sbuf, tbuf, N);
    k_agg_ln_elu<<<node_grid, 256, 0, stream>>>(offs, csr, sbuf, tbuf, h, b0, lng, lnb, Y, N);
    // layer 1
    k_gemm_st<256><<<gemm_grid, 256, 0, stream>>>(Y, W1, as1, ad1, h, sbuf, tbuf, N);
    k_agg_ln_elu<<<node_grid, 256, 0, stream>>>(offs, csr, sbuf, tbuf, h, b1, lng, lnb, Y, N);
    // layer 2
    k_gemm2<<<node_grid, 256, 0, stream>>>(Y, W2, h2, N);
    k_agg2<<<node_grid, 256, 0, stream>>>(offs, csr, h2, as2, ad2, b2, out, N);
}

// Round 4
// 364.435 us; speedup vs baseline: 2.1103x; 1.6010x over previous
//
#include <hip/hip_runtime.h>
#include <math.h>

constexpr float NEG_SLOPE = 0.2f;
constexpr float LN_EPS = 1e-5f;

typedef __attribute__((ext_vector_type(8))) short short8;   // bf16x8 MFMA frag
typedef __attribute__((ext_vector_type(4))) float f32x4;    // MFMA acc

__device__ inline ushort f2bf(float f) {        // fp32 -> bf16 RTN-even
    uint u = __float_as_uint(f);
    u += 0x7fffu + ((u >> 16) & 1u);
    return (ushort)(u >> 16);
}

// ---------------- small helpers ----------------

__device__ inline float4 wave_max4(float4 v) {
#pragma unroll
    for (int off = 1; off < 64; off <<= 1) {
        v.x = fmaxf(v.x, __shfl_xor(v.x, off));
        v.y = fmaxf(v.y, __shfl_xor(v.y, off));
        v.z = fmaxf(v.z, __shfl_xor(v.z, off));
        v.w = fmaxf(v.w, __shfl_xor(v.w, off));
    }
    return v;
}

__device__ inline float4 wave_sum4(float4 v) {
#pragma unroll
    for (int off = 1; off < 64; off <<= 1) {
        v.x += __shfl_xor(v.x, off);
        v.y += __shfl_xor(v.y, off);
        v.z += __shfl_xor(v.z, off);
        v.w += __shfl_xor(v.w, off);
    }
    return v;
}

__device__ inline float pick4(float4 v, int h) {
    float r = v.x;
    r = (h == 1) ? v.y : r;
    r = (h == 2) ? v.z : r;
    r = (h == 3) ? v.w : r;
    return r;
}

// ---------------- dtype conversion pre-passes ----------------

__global__ void k_cvt_bf16(const float* __restrict__ in, ushort* __restrict__ out, int n8) {
    int i = blockIdx.x * blockDim.x + threadIdx.x;
    if (i >= n8) return;
    float4 a = *reinterpret_cast<const float4*>(in + (size_t)i * 8);
    float4 b = *reinterpret_cast<const float4*>(in + (size_t)i * 8 + 4);
    ushort u[8] = {f2bf(a.x), f2bf(a.y), f2bf(a.z), f2bf(a.w),
                   f2bf(b.x), f2bf(b.y), f2bf(b.z), f2bf(b.w)};
    *reinterpret_cast<uint4*>(out + (size_t)i * 8) = *reinterpret_cast<const uint4*>(u);
}

// Wt[c][k] = bf16(W[k][c]) ; W is [K][256]
__global__ void k_cvt_wt(const float* __restrict__ W, ushort* __restrict__ Wt, int K) {
    int idx = blockIdx.x * blockDim.x + threadIdx.x;
    if (idx >= K * 256) return;
    int k = idx >> 8, c = idx & 255;
    Wt[(size_t)c * K + k] = f2bf(W[idx]);
}

// ---------------- CSR build ----------------

__global__ void k_zero(int* __restrict__ p, int n) {
    int i = blockIdx.x * blockDim.x + threadIdx.x;
    if (i < n) p[i] = 0;
}

__global__ void k_hist(const int* __restrict__ ei, int E, int N, int* __restrict__ cnt) {
    int i = blockIdx.x * blockDim.x + threadIdx.x;
    if (i >= E + N) return;
    int dst = (i < E) ? ei[E + i] : (i - E);
    atomicAdd(&cnt[dst], 1);
}

__global__ __launch_bounds__(1024) void k_scan1(const int* __restrict__ cnt,
                                                int* __restrict__ offs,
                                                int* __restrict__ bsum, int n) {
    __shared__ int wsum[16];
    const int lane = threadIdx.x & 63;
    const int w = threadIdx.x >> 6;
    int i = blockIdx.x * 1024 + threadIdx.x;
    int v = (i < n) ? cnt[i] : 0;
#pragma unroll
    for (int off = 1; off < 64; off <<= 1) {
        int u = __shfl_up(v, off);
        if (lane >= off) v += u;
    }
    if (lane == 63) wsum[w] = v;
    __syncthreads();
    if (w == 0) {
        int x = (lane < 16) ? wsum[lane] : 0;
#pragma unroll
        for (int off = 1; off < 16; off <<= 1) {
            int u = __shfl_up(x, off);
            if (lane >= off) x += u;
        }
        if (lane < 16) wsum[lane] = x;
    }
    __syncthreads();
    v += (w > 0) ? wsum[w - 1] : 0;
    if (i < n) offs[i + 1] = v;
    if (threadIdx.x == 1023) bsum[blockIdx.x] = v;
}

__global__ __launch_bounds__(1024) void k_scan2(const int* __restrict__ bsum,
                                                int* __restrict__ bcarry, int nb) {
    __shared__ int wsum[16];
    const int lane = threadIdx.x & 63;
    const int w = threadIdx.x >> 6;
    int v0 = ((int)threadIdx.x < nb) ? bsum[threadIdx.x] : 0;
    int v = v0;
#pragma unroll
    for (int off = 1; off < 64; off <<= 1) {
        int u = __shfl_up(v, off);
        if (lane >= off) v += u;
    }
    if (lane == 63) wsum[w] = v;
    __syncthreads();
    if (w == 0) {
        int x = (lane < 16) ? wsum[lane] : 0;
#pragma unroll
        for (int off = 1; off < 16; off <<= 1) {
            int u = __shfl_up(x, off);
            if (lane >= off) x += u;
        }
        if (lane < 16) wsum[lane] = x;
    }
    __syncthreads();
    v += (w > 0) ? wsum[w - 1] : 0;
    if ((int)threadIdx.x < nb) bcarry[threadIdx.x] = v - v0;
}

__global__ void k_scan3(int* __restrict__ offs, const int* __restrict__ bcarry, int n) {
    int i = blockIdx.x * blockDim.x + threadIdx.x;
    if (i == 0) offs[0] = 0;
    if (i < n) offs[i + 1] += bcarry[i >> 10];
}

__global__ void k_copy(const int* __restrict__ a, int* __restrict__ b, int n) {
    int i = blockIdx.x * blockDim.x + threadIdx.x;
    if (i < n) b[i] = a[i];
}

__global__ void k_scatter(const int* __restrict__ ei, int E, int N,
                          int* __restrict__ cursor, int* __restrict__ csr) {
    int i = blockIdx.x * blockDim.x + threadIdx.x;
    if (i >= E + N) return;
    int src, dst;
    if (i < E) { src = ei[i]; dst = ei[E + i]; }
    else       { src = i - E; dst = i - E; }
    int pos = atomicAdd(&cursor[dst], 1);
    csr[pos] = src;
}

// ---------------- MFMA GEMM: h = Xb * W  (+ fused s,t scores) ----------------
// Xb: [N][K] bf16, Wt: [256][K] bf16 (W transposed), h: [N][256] bf16,
// s,t: [N][4] fp32.  Block = 256 thr (4 waves), block covers 64 rows x 64 cols
// (one head). B-frags held in registers (32 frags @ K=256); A from global.
// mfma_f32_16x16x32_bf16 layout (m89/m97-verified): A/B lane l&15 = row/col,
// l>>4 = k-octet (16B contiguous); C col = l&15, row = (l>>4)*4 + reg.

template <int K>
__global__ __launch_bounds__(256, 2) void k_gemm_mfma(
    const ushort* __restrict__ Xb, const ushort* __restrict__ Wt,
    const float* __restrict__ a_s, const float* __restrict__ a_d,
    ushort* __restrict__ h, float* __restrict__ s, float* __restrict__ t, int N)
{
    constexpr int KC = K / 32;
    const int tid = threadIdx.x;
    const int w = tid >> 6;
    const int l = tid & 63;
    const int lr = l & 15;
    const int lk = l >> 4;
    const int slice = blockIdx.x & 3;       // head / 64-col slice
    const int rowblk = blockIdx.x >> 2;
    const int row0 = rowblk * 64 + w * 16;  // this wave's 16 rows

    // B fragments in registers
    short8 b[4][KC];
#pragma unroll
    for (int ct = 0; ct < 4; ++ct) {
        const ushort* wp = Wt + (size_t)(slice * 64 + ct * 16 + lr) * K + lk * 8;
#pragma unroll
        for (int kc = 0; kc < KC; ++kc)
            b[ct][kc] = *reinterpret_cast<const short8*>(wp + kc * 32);
    }

    // A fragments
    int arow = row0 + lr;
    arow = (arow < N) ? arow : (N - 1);
    const ushort* xp = Xb + (size_t)arow * K + lk * 8;
    short8 a[KC];
#pragma unroll
    for (int kc = 0; kc < KC; ++kc)
        a[kc] = *reinterpret_cast<const short8*>(xp + kc * 32);

    f32x4 acc[4];
#pragma unroll
    for (int ct = 0; ct < 4; ++ct) acc[ct] = (f32x4){0.f, 0.f, 0.f, 0.f};

#pragma unroll
    for (int ct = 0; ct < 4; ++ct)
#pragma unroll
        for (int kc = 0; kc < KC; ++kc)
            acc[ct] = __builtin_amdgcn_mfma_f32_16x16x32_bf16(a[kc], b[ct][kc], acc[ct], 0, 0, 0);

    // epilogue: h (bf16) + fused s,t
    float asv[4], adv[4];
#pragma unroll
    for (int ct = 0; ct < 4; ++ct) {
        asv[ct] = a_s[slice * 64 + ct * 16 + lr];
        adv[ct] = a_d[slice * 64 + ct * 16 + lr];
    }
    float ps[4] = {0.f, 0.f, 0.f, 0.f}, pt[4] = {0.f, 0.f, 0.f, 0.f};
#pragma unroll
    for (int j = 0; j < 4; ++j) {
        int row = row0 + lk * 4 + j;
        bool ok = row < N;
#pragma unroll
        for (int ct = 0; ct < 4; ++ct) {
            float v = acc[ct][j];
            ps[j] = fmaf(v, asv[ct], ps[j]);
            pt[j] = fmaf(v, adv[ct], pt[j]);
            if (ok) h[(size_t)row * 256 + slice * 64 + ct * 16 + lr] = f2bf(v);
        }
    }
#pragma unroll
    for (int j = 0; j < 4; ++j) {
#pragma unroll
        for (int o = 1; o < 16; o <<= 1) {
            ps[j] += __shfl_xor(ps[j], o);
            pt[j] += __shfl_xor(pt[j], o);
        }
    }
    if (lr == 0) {
#pragma unroll
        for (int j = 0; j < 4; ++j) {
            int row = row0 + lk * 4 + j;
            if (row < N) {
                s[(size_t)row * 4 + slice] = ps[j];
                t[(size_t)row * 4 + slice] = pt[j];
            }
        }
    }
}

// ---------------- aggregation (+ bias + LayerNorm + ELU) ----------------
// one wave per destination node; lane owns 4 channels (8B bf16); head=lane>>4.
// Online-softmax single pass; p/src parked in LDS; h gathered as bf16.

__global__ __launch_bounds__(256) void k_agg_ln_elu(
    const int* __restrict__ offs, const int* __restrict__ csr,
    const float* __restrict__ s, const float* __restrict__ t,
    const ushort* __restrict__ h, const float* __restrict__ bias,
    const float* __restrict__ lng, const float* __restrict__ lnb,
    ushort* __restrict__ Y, int N)
{
    __shared__ float p_s[4][256];
    __shared__ int src_s[4][64];

    const int wid = threadIdx.x >> 6;
    const int lane = threadIdx.x & 63;
    const int n = blockIdx.x * 4 + wid;
    if (n >= N) return;
    const int head = lane >> 4;
    const float4 t4 = *reinterpret_cast<const float4*>(t + (size_t)n * 4);
    const int beg = offs[n], end = offs[n + 1];

    float4 m4 = make_float4(-1e30f, -1e30f, -1e30f, -1e30f);
    float4 den4 = make_float4(0.f, 0.f, 0.f, 0.f);
    float4 acc = make_float4(0.f, 0.f, 0.f, 0.f);

    for (int base = beg; base < end; base += 64) {
        const int cnt = min(64, end - base);
        int src = 0;
        float4 e4 = make_float4(-1e30f, -1e30f, -1e30f, -1e30f);
        if (lane < cnt) {
            src = csr[base + lane];
            float4 sv = *reinterpret_cast<const float4*>(s + (size_t)src * 4);
            float ex = sv.x + t4.x, ey = sv.y + t4.y, ez = sv.z + t4.z, ew = sv.w + t4.w;
            e4.x = (ex > 0.f) ? ex : NEG_SLOPE * ex;
            e4.y = (ey > 0.f) ? ey : NEG_SLOPE * ey;
            e4.z = (ez > 0.f) ? ez : NEG_SLOPE * ez;
            e4.w = (ew > 0.f) ? ew : NEG_SLOPE * ew;
        }
        float4 bm = wave_max4(e4);
        float4 newm = make_float4(fmaxf(m4.x, bm.x), fmaxf(m4.y, bm.y),
                                  fmaxf(m4.z, bm.z), fmaxf(m4.w, bm.w));
        float4 sc4 = make_float4(__expf(m4.x - newm.x), __expf(m4.y - newm.y),
                                 __expf(m4.z - newm.z), __expf(m4.w - newm.w));
        m4 = newm;
        float sch = pick4(sc4, head);
        acc.x *= sch; acc.y *= sch; acc.z *= sch; acc.w *= sch;
        float4 p4 = make_float4(__expf(e4.x - newm.x), __expf(e4.y - newm.y),
                                __expf(e4.z - newm.z), __expf(e4.w - newm.w));
        den4.x = den4.x * sc4.x + p4.x;
        den4.y = den4.y * sc4.y + p4.y;
        den4.z = den4.z * sc4.z + p4.z;
        den4.w = den4.w * sc4.w + p4.w;

        *reinterpret_cast<float4*>(&p_s[wid][lane * 4]) = p4;
        src_s[wid][lane] = src;
        __builtin_amdgcn_s_waitcnt(0);

        const uint* hb = reinterpret_cast<const uint*>(h) + lane * 2;
#pragma unroll 4
        for (int jj = 0; jj < cnt; ++jj) {
            int srcj = src_s[wid][jj];
            float pj = p_s[wid][jj * 4 + head];
            uint2 uv = *reinterpret_cast<const uint2*>(hb + (size_t)srcj * 128);
            acc.x = fmaf(pj, __uint_as_float(uv.x << 16), acc.x);
            acc.y = fmaf(pj, __uint_as_float(uv.x & 0xffff0000u), acc.y);
            acc.z = fmaf(pj, __uint_as_float(uv.y << 16), acc.z);
            acc.w = fmaf(pj, __uint_as_float(uv.y & 0xffff0000u), acc.w);
        }
    }

    float4 dsum = wave_sum4(den4);
    const float inv = 1.0f / pick4(dsum, head);
    float4 bv = *reinterpret_cast<const float4*>(bias + lane * 4);
    float v0 = acc.x * inv + bv.x;
    float v1 = acc.y * inv + bv.y;
    float v2 = acc.z * inv + bv.z;
    float v3 = acc.w * inv + bv.w;

    float sum = v0 + v1 + v2 + v3;
#pragma unroll
    for (int o = 32; o >= 1; o >>= 1) sum += __shfl_xor(sum, o);
    float mu = sum * (1.0f / 256.0f);
    float d0 = v0 - mu, d1 = v1 - mu, d2 = v2 - mu, d3 = v3 - mu;
    float vs = d0 * d0 + d1 * d1 + d2 * d2 + d3 * d3;
#pragma unroll
    for (int o = 32; o >= 1; o >>= 1) vs += __shfl_xor(vs, o);
    float rstd = rsqrtf(vs * (1.0f / 256.0f) + LN_EPS);
    float4 gv = *reinterpret_cast<const float4*>(lng + lane * 4);
    float4 bb = *reinterpret_cast<const float4*>(lnb + lane * 4);
    float o0 = d0 * rstd * gv.x + bb.x;
    float o1 = d1 * rstd * gv.y + bb.y;
    float o2 = d2 * rstd * gv.z + bb.z;
    float o3 = d3 * rstd * gv.w + bb.w;
    o0 = (o0 > 0.f) ? o0 : (expf(o0) - 1.0f);
    o1 = (o1 > 0.f) ? o1 : (expf(o1) - 1.0f);
    o2 = (o2 > 0.f) ? o2 : (expf(o2) - 1.0f);
    o3 = (o3 > 0.f) ? o3 : (expf(o3) - 1.0f);
    ushort yo[4] = {f2bf(o0), f2bf(o1), f2bf(o2), f2bf(o3)};
    *reinterpret_cast<uint2*>(Y + (size_t)n * 256 + lane * 4) =
        *reinterpret_cast<const uint2*>(yo);
}

// ---------------- layer 2: h2 = Y * W2 (256->1), Y bf16 ----------------

__global__ __launch_bounds__(256) void k_gemm2(
    const ushort* __restrict__ Y, const float* __restrict__ W2,
    float* __restrict__ h2, int N)
{
    const int wid = threadIdx.x >> 6;
    const int lane = threadIdx.x & 63;
    const int n = blockIdx.x * 4 + wid;
    if (n >= N) return;
    uint2 uv = *reinterpret_cast<const uint2*>(
        reinterpret_cast<const uint*>(Y) + (size_t)n * 128 + lane * 2);
    float4 wv = *reinterpret_cast<const float4*>(W2 + lane * 4);
    float p = __uint_as_float(uv.x << 16) * wv.x
            + __uint_as_float(uv.x & 0xffff0000u) * wv.y
            + __uint_as_float(uv.y << 16) * wv.z
            + __uint_as_float(uv.y & 0xffff0000u) * wv.w;
#pragma unroll
    for (int o = 32; o >= 1; o >>= 1) p += __shfl_xor(p, o);
    if (lane == 0) h2[n] = p;
}

// ---------------- layer 2 aggregation (H=1, C=1) ----------------

__global__ __launch_bounds__(256) void k_agg2(
    const int* __restrict__ offs, const int* __restrict__ csr,
    const float* __restrict__ h2,
    const float* __restrict__ as2, const float* __restrict__ ad2,
    const float* __restrict__ b2, float* __restrict__ out, int N)
{
    const int wid = threadIdx.x >> 6;
    const int lane = threadIdx.x & 63;
    const int n = blockIdx.x * 4 + wid;
    if (n >= N) return;
    const float asv = as2[0], adv = ad2[0];
    const float tval = adv * h2[n];
    const int beg = offs[n], end = offs[n + 1];

    float m = -1e30f;
    for (int i = beg + lane; i < end; i += 64) {
        float e = asv * h2[csr[i]] + tval;
        e = (e > 0.f) ? e : NEG_SLOPE * e;
        m = fmaxf(m, e);
    }
#pragma unroll
    for (int o = 32; o >= 1; o >>= 1) m = fmaxf(m, __shfl_xor(m, o));
    float den = 0.f, num = 0.f;
    for (int i = beg + lane; i < end; i += 64) {
        float hv = h2[csr[i]];
        float e = asv * hv + tval;
        e = (e > 0.f) ? e : NEG_SLOPE * e;
        float p = __expf(e - m);
        den += p;
        num = fmaf(p, hv, num);
    }
#pragma unroll
    for (int o = 32; o >= 1; o >>= 1) { den += __shfl_xor(den, o); num += __shfl_xor(num, o); }
    if (lane == 0) out[n] = num / den + b2[0];
}

// ---------------- launch ----------------

extern "C" void kernel_launch(void* const* d_in, const int* in_sizes, int n_in,
                              void* d_out, int out_size, void* d_ws, size_t ws_size,
                              hipStream_t stream) {
    const float* x   = (const float*)d_in[0];
    const int*   ei  = (const int*)d_in[1];
    const float* W0  = (const float*)d_in[2];
    const float* as0 = (const float*)d_in[3];
    const float* ad0 = (const float*)d_in[4];
    const float* b0  = (const float*)d_in[5];
    const float* W1  = (const float*)d_in[6];
    const float* as1 = (const float*)d_in[7];
    const float* ad1 = (const float*)d_in[8];
    const float* b1  = (const float*)d_in[9];
    const float* W2  = (const float*)d_in[10];
    const float* as2 = (const float*)d_in[11];
    const float* ad2 = (const float*)d_in[12];
    const float* b2  = (const float*)d_in[13];
    const float* lng = (const float*)d_in[14];
    const float* lnb = (const float*)d_in[15];

    const int N = in_sizes[0] / 64;
    const int E = in_sizes[1] / 2;
    const int TOT = E + N;
    const int NB = (N + 1023) / 1024;

    char* w = (char*)d_ws;
    auto alloc = [&](size_t bytes) -> void* {
        void* p = (void*)w;
        w += (bytes + 255) & ~(size_t)255;
        return p;
    };
    int*    cnt    = (int*)alloc(sizeof(int) * N);
    int*    offs   = (int*)alloc(sizeof(int) * (N + 1));
    int*    cursor = (int*)alloc(sizeof(int) * N);
    int*    csr    = (int*)alloc(sizeof(int) * TOT);
    int*    bsum   = (int*)alloc(sizeof(int) * (NB + 1));
    int*    bcarry = (int*)alloc(sizeof(int) * (NB + 1));
    float*  sbuf   = (float*)alloc(sizeof(float) * N * 4);
    float*  tbuf   = (float*)alloc(sizeof(float) * N * 4);
    ushort* Xb     = (ushort*)alloc(sizeof(ushort) * (size_t)N * 64);
    ushort* Wt0    = (ushort*)alloc(sizeof(ushort) * 256 * 64);
    ushort* Wt1    = (ushort*)alloc(sizeof(ushort) * 256 * 256);
    ushort* hbf    = (ushort*)alloc(sizeof(ushort) * (size_t)N * 256);
    ushort* Yb     = (ushort*)alloc(sizeof(ushort) * (size_t)N * 256);
    float*  h2     = (float*)alloc(sizeof(float) * N);
    float*  out    = (float*)d_out;

    // dtype pre-passes
    k_cvt_bf16<<<(N * 8 + 255) / 256, 256, 0, stream>>>(x, Xb, N * 8);
    k_cvt_wt<<<(64 * 256 + 255) / 256, 256, 0, stream>>>(W0, Wt0, 64);
    k_cvt_wt<<<(256 * 256 + 255) / 256, 256, 0, stream>>>(W1, Wt1, 256);

    // CSR build
    k_zero<<<(N + 255) / 256, 256, 0, stream>>>(cnt, N);
    k_hist<<<(TOT + 255) / 256, 256, 0, stream>>>(ei, E, N, cnt);
    k_scan1<<<NB, 1024, 0, stream>>>(cnt, offs, bsum, N);
    k_scan2<<<1, 1024, 0, stream>>>(bsum, bcarry, NB);
    k_scan3<<<(N + 255) / 256, 256, 0, stream>>>(offs, bcarry, N);
    k_copy<<<(N + 255) / 256, 256, 0, stream>>>(offs, cursor, N);
    k_scatter<<<(TOT + 255) / 256, 256, 0, stream>>>(ei, E, N, cursor, csr);

    const int gemm_grid = ((N + 63) / 64) * 4;
    const int node_grid = (N + 3) / 4;

    // layer 0
    k_gemm_mfma<64><<<gemm_grid, 256, 0, stream>>>(Xb, Wt0, as0, ad0, hbf, sbuf, tbuf, N);
    k_agg_ln_elu<<<node_grid, 256, 0, stream>>>(offs, csr, sbuf, tbuf, hbf, b0, lng, lnb, Yb, N);
    // layer 1
    k_gemm_mfma<256><<<gemm_grid, 256, 0, stream>>>(Yb, Wt1, as1, ad1, hbf, sbuf, tbuf, N);
    k_agg_ln_elu<<<node_grid, 256, 0, stream>>>(offs, csr, sbuf, tbuf, hbf, b1, lng, lnb, Yb, N);
    // layer 2
    k_gemm2<<<node_grid, 256, 0, stream>>>(Yb, W2, h2, N);
    k_agg2<<<node_grid, 256, 0, stream>>>(offs, csr, h2, as2, ad2, b2, out, N);
}

// Round 5
// 346.339 us; speedup vs baseline: 2.2206x; 1.0523x over previous
//
#include <hip/hip_runtime.h>
#include <math.h>

constexpr float NEG_SLOPE = 0.2f;
constexpr float LN_EPS = 1e-5f;

typedef __attribute__((ext_vector_type(8))) short short8;   // bf16x8 MFMA frag
typedef __attribute__((ext_vector_type(4))) float f32x4;    // MFMA acc

__device__ inline ushort f2bf(float f) {        // fp32 -> bf16 RTN-even
    uint u = __float_as_uint(f);
    u += 0x7fffu + ((u >> 16) & 1u);
    return (ushort)(u >> 16);
}
__device__ inline float bf_lo(uint u) { return __uint_as_float(u << 16); }
__device__ inline float bf_hi(uint u) { return __uint_as_float(u & 0xffff0000u); }

// ---------------- small helpers ----------------

__device__ inline float4 wave_max4(float4 v) {
#pragma unroll
    for (int off = 1; off < 64; off <<= 1) {
        v.x = fmaxf(v.x, __shfl_xor(v.x, off));
        v.y = fmaxf(v.y, __shfl_xor(v.y, off));
        v.z = fmaxf(v.z, __shfl_xor(v.z, off));
        v.w = fmaxf(v.w, __shfl_xor(v.w, off));
    }
    return v;
}

__device__ inline float4 wave_sum4(float4 v) {
#pragma unroll
    for (int off = 1; off < 64; off <<= 1) {
        v.x += __shfl_xor(v.x, off);
        v.y += __shfl_xor(v.y, off);
        v.z += __shfl_xor(v.z, off);
        v.w += __shfl_xor(v.w, off);
    }
    return v;
}

__device__ inline float pick4(float4 v, int h) {
    float r = v.x;
    r = (h == 1) ? v.y : r;
    r = (h == 2) ? v.z : r;
    r = (h == 3) ? v.w : r;
    return r;
}

// ---------------- dtype conversion pre-passes ----------------

__global__ void k_cvt_bf16(const float* __restrict__ in, ushort* __restrict__ out, int n8) {
    int i = blockIdx.x * blockDim.x + threadIdx.x;
    if (i >= n8) return;
    float4 a = *reinterpret_cast<const float4*>(in + (size_t)i * 8);
    float4 b = *reinterpret_cast<const float4*>(in + (size_t)i * 8 + 4);
    ushort u[8] = {f2bf(a.x), f2bf(a.y), f2bf(a.z), f2bf(a.w),
                   f2bf(b.x), f2bf(b.y), f2bf(b.z), f2bf(b.w)};
    *reinterpret_cast<uint4*>(out + (size_t)i * 8) = *reinterpret_cast<const uint4*>(u);
}

// Wt[c][k] = bf16(W[k][c]) ; W is [K][256]
__global__ void k_cvt_wt(const float* __restrict__ W, ushort* __restrict__ Wt, int K) {
    int idx = blockIdx.x * blockDim.x + threadIdx.x;
    if (idx >= K * 256) return;
    int k = idx >> 8, c = idx & 255;
    Wt[(size_t)c * K + k] = f2bf(W[idx]);
}

// ---------------- CSR build ----------------

__global__ void k_zero(int* __restrict__ p, int n) {
    int i = blockIdx.x * blockDim.x + threadIdx.x;
    if (i < n) p[i] = 0;
}

__global__ void k_hist(const int* __restrict__ ei, int E, int N, int* __restrict__ cnt) {
    int i = blockIdx.x * blockDim.x + threadIdx.x;
    if (i >= E + N) return;
    int dst = (i < E) ? ei[E + i] : (i - E);
    atomicAdd(&cnt[dst], 1);
}

__global__ __launch_bounds__(1024) void k_scan1(const int* __restrict__ cnt,
                                                int* __restrict__ offs,
                                                int* __restrict__ bsum, int n) {
    __shared__ int wsum[16];
    const int lane = threadIdx.x & 63;
    const int w = threadIdx.x >> 6;
    int i = blockIdx.x * 1024 + threadIdx.x;
    int v = (i < n) ? cnt[i] : 0;
#pragma unroll
    for (int off = 1; off < 64; off <<= 1) {
        int u = __shfl_up(v, off);
        if (lane >= off) v += u;
    }
    if (lane == 63) wsum[w] = v;
    __syncthreads();
    if (w == 0) {
        int x = (lane < 16) ? wsum[lane] : 0;
#pragma unroll
        for (int off = 1; off < 16; off <<= 1) {
            int u = __shfl_up(x, off);
            if (lane >= off) x += u;
        }
        if (lane < 16) wsum[lane] = x;
    }
    __syncthreads();
    v += (w > 0) ? wsum[w - 1] : 0;
    if (i < n) offs[i + 1] = v;
    if (threadIdx.x == 1023) bsum[blockIdx.x] = v;
}

__global__ __launch_bounds__(1024) void k_scan2(const int* __restrict__ bsum,
                                                int* __restrict__ bcarry, int nb) {
    __shared__ int wsum[16];
    const int lane = threadIdx.x & 63;
    const int w = threadIdx.x >> 6;
    int v0 = ((int)threadIdx.x < nb) ? bsum[threadIdx.x] : 0;
    int v = v0;
#pragma unroll
    for (int off = 1; off < 64; off <<= 1) {
        int u = __shfl_up(v, off);
        if (lane >= off) v += u;
    }
    if (lane == 63) wsum[w] = v;
    __syncthreads();
    if (w == 0) {
        int x = (lane < 16) ? wsum[lane] : 0;
#pragma unroll
        for (int off = 1; off < 16; off <<= 1) {
            int u = __shfl_up(x, off);
            if (lane >= off) x += u;
        }
        if (lane < 16) wsum[lane] = x;
    }
    __syncthreads();
    v += (w > 0) ? wsum[w - 1] : 0;
    if ((int)threadIdx.x < nb) bcarry[threadIdx.x] = v - v0;
}

// finalize offs and also write cursor = segment starts
__global__ void k_scan3(int* __restrict__ offs, const int* __restrict__ bcarry,
                        int* __restrict__ cursor, int n) {
    int i = blockIdx.x * blockDim.x + threadIdx.x;
    if (i == 0) { offs[0] = 0; cursor[0] = 0; }
    if (i < n) {
        int v = offs[i + 1] + bcarry[i >> 10];
        offs[i + 1] = v;
        if (i + 1 < n) cursor[i + 1] = v;
    }
}

__global__ void k_scatter(const int* __restrict__ ei, int E, int N,
                          int* __restrict__ cursor, int* __restrict__ csr) {
    int i = blockIdx.x * blockDim.x + threadIdx.x;
    if (i >= E + N) return;
    int src, dst;
    if (i < E) { src = ei[i]; dst = ei[E + i]; }
    else       { src = i - E; dst = i - E; }
    int pos = atomicAdd(&cursor[dst], 1);
    csr[pos] = src;
}

// ---------------- MFMA GEMM: h = Xb * W  (+ fused s,t scores) ----------------
// Xb: [N][K] bf16, Wt: [256][K] bf16 (W transposed), h: [N][256] bf16,
// s,t: [N][4] fp32.  Block = 256 thr (4 waves); block covers 64 rows x 64 cols.
// mfma_f32_16x16x32_bf16: A/B lane l&15 = row/col, l>>4 = k-octet (16B);
// C col = l&15, row = (l>>4)*4 + reg.

template <int K>
__global__ __launch_bounds__(256, 2) void k_gemm_mfma(
    const ushort* __restrict__ Xb, const ushort* __restrict__ Wt,
    const float* __restrict__ a_s, const float* __restrict__ a_d,
    ushort* __restrict__ h, float* __restrict__ s, float* __restrict__ t, int N)
{
    constexpr int KC = K / 32;
    const int tid = threadIdx.x;
    const int w = tid >> 6;
    const int l = tid & 63;
    const int lr = l & 15;
    const int lk = l >> 4;
    const int slice = blockIdx.x & 3;
    const int rowblk = blockIdx.x >> 2;
    const int row0 = rowblk * 64 + w * 16;

    short8 b[4][KC];
#pragma unroll
    for (int ct = 0; ct < 4; ++ct) {
        const ushort* wp = Wt + (size_t)(slice * 64 + ct * 16 + lr) * K + lk * 8;
#pragma unroll
        for (int kc = 0; kc < KC; ++kc)
            b[ct][kc] = *reinterpret_cast<const short8*>(wp + kc * 32);
    }

    int arow = row0 + lr;
    arow = (arow < N) ? arow : (N - 1);
    const ushort* xp = Xb + (size_t)arow * K + lk * 8;
    short8 a[KC];
#pragma unroll
    for (int kc = 0; kc < KC; ++kc)
        a[kc] = *reinterpret_cast<const short8*>(xp + kc * 32);

    f32x4 acc[4];
#pragma unroll
    for (int ct = 0; ct < 4; ++ct) acc[ct] = (f32x4){0.f, 0.f, 0.f, 0.f};

#pragma unroll
    for (int ct = 0; ct < 4; ++ct)
#pragma unroll
        for (int kc = 0; kc < KC; ++kc)
            acc[ct] = __builtin_amdgcn_mfma_f32_16x16x32_bf16(a[kc], b[ct][kc], acc[ct], 0, 0, 0);

    float asv[4], adv[4];
#pragma unroll
    for (int ct = 0; ct < 4; ++ct) {
        asv[ct] = a_s[slice * 64 + ct * 16 + lr];
        adv[ct] = a_d[slice * 64 + ct * 16 + lr];
    }
    float ps[4] = {0.f, 0.f, 0.f, 0.f}, pt[4] = {0.f, 0.f, 0.f, 0.f};
#pragma unroll
    for (int j = 0; j < 4; ++j) {
        int row = row0 + lk * 4 + j;
        bool ok = row < N;
#pragma unroll
        for (int ct = 0; ct < 4; ++ct) {
            float v = acc[ct][j];
            ps[j] = fmaf(v, asv[ct], ps[j]);
            pt[j] = fmaf(v, adv[ct], pt[j]);
            if (ok) h[(size_t)row * 256 + slice * 64 + ct * 16 + lr] = f2bf(v);
        }
    }
#pragma unroll
    for (int j = 0; j < 4; ++j) {
#pragma unroll
        for (int o = 1; o < 16; o <<= 1) {
            ps[j] += __shfl_xor(ps[j], o);
            pt[j] += __shfl_xor(pt[j], o);
        }
    }
    if (lr == 0) {
#pragma unroll
        for (int j = 0; j < 4; ++j) {
            int row = row0 + lk * 4 + j;
            if (row < N) {
                s[(size_t)row * 4 + slice] = ps[j];
                t[(size_t)row * 4 + slice] = pt[j];
            }
        }
    }
}

// ---------------- aggregation (+ bias + LayerNorm + ELU) ----------------
// one wave per destination node; lane owns 4 channels (8B bf16); head=lane>>4.
// Online softmax, single pass. p/byte-offsets parked in LDS; invalid/pad
// lanes carry p=0 so the gather loop runs padded-to-4 with no bounds checks.
// FUSE_W2: fold the 256->1 output projection into the epilogue (layer 1).

template <bool FUSE_W2>
__global__ __launch_bounds__(256) void k_agg_ln_elu(
    const int* __restrict__ offs, const int* __restrict__ csr,
    const float* __restrict__ s, const float* __restrict__ t,
    const ushort* __restrict__ h, const float* __restrict__ bias,
    const float* __restrict__ lng, const float* __restrict__ lnb,
    ushort* __restrict__ Y, const float* __restrict__ W2,
    float* __restrict__ h2, int N)
{
    __shared__ float p_s[4][256];
    __shared__ int off_s[4][64];

    const int wid = threadIdx.x >> 6;
    const int lane = threadIdx.x & 63;
    const int n = blockIdx.x * 4 + wid;
    if (n >= N) return;
    const int head = lane >> 4;
    const float4 t4 = *reinterpret_cast<const float4*>(t + (size_t)n * 4);
    const int beg = offs[n], end = offs[n + 1];

    float4 m4 = make_float4(-1e30f, -1e30f, -1e30f, -1e30f);
    float4 den4 = make_float4(0.f, 0.f, 0.f, 0.f);
    float4 acc = make_float4(0.f, 0.f, 0.f, 0.f);

    const char* hb = reinterpret_cast<const char*>(h) + lane * 8;

    for (int base = beg; base < end; base += 64) {
        const int cnt = min(64, end - base);
        int src = 0;
        float4 e4 = make_float4(-1e30f, -1e30f, -1e30f, -1e30f);
        if (lane < cnt) {
            src = csr[base + lane];
            float4 sv = *reinterpret_cast<const float4*>(s + (size_t)src * 4);
            float ex = sv.x + t4.x, ey = sv.y + t4.y, ez = sv.z + t4.z, ew = sv.w + t4.w;
            e4.x = (ex > 0.f) ? ex : NEG_SLOPE * ex;
            e4.y = (ey > 0.f) ? ey : NEG_SLOPE * ey;
            e4.z = (ez > 0.f) ? ez : NEG_SLOPE * ez;
            e4.w = (ew > 0.f) ? ew : NEG_SLOPE * ew;
        }
        float4 bm = wave_max4(e4);
        float4 newm = make_float4(fmaxf(m4.x, bm.x), fmaxf(m4.y, bm.y),
                                  fmaxf(m4.z, bm.z), fmaxf(m4.w, bm.w));
        float4 sc4 = make_float4(__expf(m4.x - newm.x), __expf(m4.y - newm.y),
                                 __expf(m4.z - newm.z), __expf(m4.w - newm.w));
        m4 = newm;
        float sch = pick4(sc4, head);
        acc.x *= sch; acc.y *= sch; acc.z *= sch; acc.w *= sch;
        float4 p4 = make_float4(__expf(e4.x - newm.x), __expf(e4.y - newm.y),
                                __expf(e4.z - newm.z), __expf(e4.w - newm.w));
        den4.x = den4.x * sc4.x + p4.x;
        den4.y = den4.y * sc4.y + p4.y;
        den4.z = den4.z * sc4.z + p4.z;
        den4.w = den4.w * sc4.w + p4.w;

        *reinterpret_cast<float4*>(&p_s[wid][lane * 4]) = p4;
        off_s[wid][lane] = src << 9;        // byte offset of h row
        asm volatile("s_waitcnt lgkmcnt(0)" ::: "memory");

        // padded gather: entries >= cnt have p == 0 (and offset 0)
        for (int j0 = 0; j0 < cnt; j0 += 4) {
            int o0 = off_s[wid][j0 + 0];
            int o1 = off_s[wid][j0 + 1];
            int o2 = off_s[wid][j0 + 2];
            int o3 = off_s[wid][j0 + 3];
            float q0 = p_s[wid][(j0 + 0) * 4 + head];
            float q1 = p_s[wid][(j0 + 1) * 4 + head];
            float q2 = p_s[wid][(j0 + 2) * 4 + head];
            float q3 = p_s[wid][(j0 + 3) * 4 + head];
            uint2 u0 = *reinterpret_cast<const uint2*>(hb + o0);
            uint2 u1 = *reinterpret_cast<const uint2*>(hb + o1);
            uint2 u2 = *reinterpret_cast<const uint2*>(hb + o2);
            uint2 u3 = *reinterpret_cast<const uint2*>(hb + o3);
            acc.x = fmaf(q0, bf_lo(u0.x), acc.x);
            acc.y = fmaf(q0, bf_hi(u0.x), acc.y);
            acc.z = fmaf(q0, bf_lo(u0.y), acc.z);
            acc.w = fmaf(q0, bf_hi(u0.y), acc.w);
            acc.x = fmaf(q1, bf_lo(u1.x), acc.x);
            acc.y = fmaf(q1, bf_hi(u1.x), acc.y);
            acc.z = fmaf(q1, bf_lo(u1.y), acc.z);
            acc.w = fmaf(q1, bf_hi(u1.y), acc.w);
            acc.x = fmaf(q2, bf_lo(u2.x), acc.x);
            acc.y = fmaf(q2, bf_hi(u2.x), acc.y);
            acc.z = fmaf(q2, bf_lo(u2.y), acc.z);
            acc.w = fmaf(q2, bf_hi(u2.y), acc.w);
            acc.x = fmaf(q3, bf_lo(u3.x), acc.x);
            acc.y = fmaf(q3, bf_hi(u3.x), acc.y);
            acc.z = fmaf(q3, bf_lo(u3.y), acc.z);
            acc.w = fmaf(q3, bf_hi(u3.y), acc.w);
        }
    }

    float4 dsum = wave_sum4(den4);
    const float inv = 1.0f / pick4(dsum, head);
    float4 bv = *reinterpret_cast<const float4*>(bias + lane * 4);
    float v0 = acc.x * inv + bv.x;
    float v1 = acc.y * inv + bv.y;
    float v2 = acc.z * inv + bv.z;
    float v3 = acc.w * inv + bv.w;

    float sum = v0 + v1 + v2 + v3;
#pragma unroll
    for (int o = 32; o >= 1; o >>= 1) sum += __shfl_xor(sum, o);
    float mu = sum * (1.0f / 256.0f);
    float d0 = v0 - mu, d1 = v1 - mu, d2 = v2 - mu, d3 = v3 - mu;
    float vs = d0 * d0 + d1 * d1 + d2 * d2 + d3 * d3;
#pragma unroll
    for (int o = 32; o >= 1; o >>= 1) vs += __shfl_xor(vs, o);
    float rstd = rsqrtf(vs * (1.0f / 256.0f) + LN_EPS);
    float4 gv = *reinterpret_cast<const float4*>(lng + lane * 4);
    float4 bb = *reinterpret_cast<const float4*>(lnb + lane * 4);
    float o0 = d0 * rstd * gv.x + bb.x;
    float o1 = d1 * rstd * gv.y + bb.y;
    float o2 = d2 * rstd * gv.z + bb.z;
    float o3 = d3 * rstd * gv.w + bb.w;
    o0 = (o0 > 0.f) ? o0 : (expf(o0) - 1.0f);
    o1 = (o1 > 0.f) ? o1 : (expf(o1) - 1.0f);
    o2 = (o2 > 0.f) ? o2 : (expf(o2) - 1.0f);
    o3 = (o3 > 0.f) ? o3 : (expf(o3) - 1.0f);

    if (FUSE_W2) {
        float4 wv = *reinterpret_cast<const float4*>(W2 + lane * 4);
        float p = o0 * wv.x + o1 * wv.y + o2 * wv.z + o3 * wv.w;
#pragma unroll
        for (int o = 32; o >= 1; o >>= 1) p += __shfl_xor(p, o);
        if (lane == 0) h2[n] = p;
    } else {
        ushort yo[4] = {f2bf(o0), f2bf(o1), f2bf(o2), f2bf(o3)};
        *reinterpret_cast<uint2*>(Y + (size_t)n * 256 + lane * 4) =
            *reinterpret_cast<const uint2*>(yo);
    }
}

// ---------------- layer 2 aggregation (H=1, C=1), single pass ----------------

__global__ __launch_bounds__(256) void k_agg2(
    const int* __restrict__ offs, const int* __restrict__ csr,
    const float* __restrict__ h2,
    const float* __restrict__ as2, const float* __restrict__ ad2,
    const float* __restrict__ b2, float* __restrict__ out, int N)
{
    const int wid = threadIdx.x >> 6;
    const int lane = threadIdx.x & 63;
    const int n = blockIdx.x * 4 + wid;
    if (n >= N) return;
    const float asv = as2[0], adv = ad2[0];
    const float tval = adv * h2[n];
    const int beg = offs[n], end = offs[n + 1];

    float m = -1e30f, den = 0.f, num = 0.f;
    for (int i = beg + lane; i < end; i += 64) {
        float hv = h2[csr[i]];
        float e = fmaf(asv, hv, tval);
        e = (e > 0.f) ? e : NEG_SLOPE * e;
        float nm = fmaxf(m, e);
        float sc = __expf(m - nm);
        float p = __expf(e - nm);
        den = den * sc + p;
        num = fmaf(num, sc, p * hv);
        m = nm;
    }
#pragma unroll
    for (int o = 1; o < 64; o <<= 1) {
        float m2 = __shfl_xor(m, o);
        float d2 = __shfl_xor(den, o);
        float n2 = __shfl_xor(num, o);
        float nm = fmaxf(m, m2);
        float sA = __expf(m - nm);
        float sB = __expf(m2 - nm);
        den = den * sA + d2 * sB;
        num = num * sA + n2 * sB;
        m = nm;
    }
    if (lane == 0) out[n] = num / den + b2[0];
}

// ---------------- launch ----------------

extern "C" void kernel_launch(void* const* d_in, const int* in_sizes, int n_in,
                              void* d_out, int out_size, void* d_ws, size_t ws_size,
                              hipStream_t stream) {
    const float* x   = (const float*)d_in[0];
    const int*   ei  = (const int*)d_in[1];
    const float* W0  = (const float*)d_in[2];
    const float* as0 = (const float*)d_in[3];
    const float* ad0 = (const float*)d_in[4];
    const float* b0  = (const float*)d_in[5];
    const float* W1  = (const float*)d_in[6];
    const float* as1 = (const float*)d_in[7];
    const float* ad1 = (const float*)d_in[8];
    const float* b1  = (const float*)d_in[9];
    const float* W2  = (const float*)d_in[10];
    const float* as2 = (const float*)d_in[11];
    const float* ad2 = (const float*)d_in[12];
    const float* b2  = (const float*)d_in[13];
    const float* lng = (const float*)d_in[14];
    const float* lnb = (const float*)d_in[15];

    const int N = in_sizes[0] / 64;
    const int E = in_sizes[1] / 2;
    const int TOT = E + N;
    const int NB = (N + 1023) / 1024;

    char* w = (char*)d_ws;
    auto alloc = [&](size_t bytes) -> void* {
        void* p = (void*)w;
        w += (bytes + 255) & ~(size_t)255;
        return p;
    };
    int*    cnt    = (int*)alloc(sizeof(int) * N);
    int*    offs   = (int*)alloc(sizeof(int) * (N + 1));
    int*    cursor = (int*)alloc(sizeof(int) * N);
    int*    csr    = (int*)alloc(sizeof(int) * TOT);
    int*    bsum   = (int*)alloc(sizeof(int) * (NB + 1));
    int*    bcarry = (int*)alloc(sizeof(int) * (NB + 1));
    float*  sbuf   = (float*)alloc(sizeof(float) * N * 4);
    float*  tbuf   = (float*)alloc(sizeof(float) * N * 4);
    ushort* Xb     = (ushort*)alloc(sizeof(ushort) * (size_t)N * 64);
    ushort* Wt0    = (ushort*)alloc(sizeof(ushort) * 256 * 64);
    ushort* Wt1    = (ushort*)alloc(sizeof(ushort) * 256 * 256);
    ushort* hbf    = (ushort*)alloc(sizeof(ushort) * (size_t)N * 256);
    ushort* Yb     = (ushort*)alloc(sizeof(ushort) * (size_t)N * 256);
    float*  h2     = (float*)alloc(sizeof(float) * N);
    float*  out    = (float*)d_out;

    // dtype pre-passes
    k_cvt_bf16<<<(N * 8 + 255) / 256, 256, 0, stream>>>(x, Xb, N * 8);
    k_cvt_wt<<<(64 * 256 + 255) / 256, 256, 0, stream>>>(W0, Wt0, 64);
    k_cvt_wt<<<(256 * 256 + 255) / 256, 256, 0, stream>>>(W1, Wt1, 256);

    // CSR build
    k_zero<<<(N + 255) / 256, 256, 0, stream>>>(cnt, N);
    k_hist<<<(TOT + 255) / 256, 256, 0, stream>>>(ei, E, N, cnt);
    k_scan1<<<NB, 1024, 0, stream>>>(cnt, offs, bsum, N);
    k_scan2<<<1, 1024, 0, stream>>>(bsum, bcarry, NB);
    k_scan3<<<(N + 255) / 256, 256, 0, stream>>>(offs, bcarry, cursor, N);
    k_scatter<<<(TOT + 255) / 256, 256, 0, stream>>>(ei, E, N, cursor, csr);

    const int gemm_grid = ((N + 63) / 64) * 4;
    const int node_grid = (N + 3) / 4;

    // layer 0
    k_gemm_mfma<64><<<gemm_grid, 256, 0, stream>>>(Xb, Wt0, as0, ad0, hbf, sbuf, tbuf, N);
    k_agg_ln_elu<false><<<node_grid, 256, 0, stream>>>(offs, csr, sbuf, tbuf, hbf,
                                                       b0, lng, lnb, Yb, nullptr, nullptr, N);
    // layer 1 (+ fused 256->1 projection)
    k_gemm_mfma<256><<<gemm_grid, 256, 0, stream>>>(Yb, Wt1, as1, ad1, hbf, sbuf, tbuf, N);
    k_agg_ln_elu<true><<<node_grid, 256, 0, stream>>>(offs, csr, sbuf, tbuf, hbf,
                                                      b1, lng, lnb, nullptr, W2, h2, N);
    // layer 2
    k_agg2<<<node_grid, 256, 0, stream>>>(offs, csr, h2, as2, ad2, b2, out, N);
}

// Round 6
// 324.628 us; speedup vs baseline: 2.3691x; 1.0669x over previous
//
#include <hip/hip_runtime.h>
#include <math.h>

constexpr float NEG_SLOPE = 0.2f;
constexpr float LN_EPS = 1e-5f;

typedef __attribute__((ext_vector_type(8))) short short8;   // bf16x8 MFMA frag
typedef __attribute__((ext_vector_type(4))) float f32x4;    // MFMA acc

__device__ inline ushort f2bf(float f) {        // fp32 -> bf16 RTN-even
    uint u = __float_as_uint(f);
    u += 0x7fffu + ((u >> 16) & 1u);
    return (ushort)(u >> 16);
}
__device__ inline float bf_lo(uint u) { return __uint_as_float(u << 16); }
__device__ inline float bf_hi(uint u) { return __uint_as_float(u & 0xffff0000u); }

__device__ inline float pick4(float4 v, int h) {
    float r = v.x;
    r = (h == 1) ? v.y : r;
    r = (h == 2) ? v.z : r;
    r = (h == 3) ? v.w : r;
    return r;
}

__device__ inline void fma8(const uint4& u, float q, float acc[8]) {
    acc[0] = fmaf(q, bf_lo(u.x), acc[0]);
    acc[1] = fmaf(q, bf_hi(u.x), acc[1]);
    acc[2] = fmaf(q, bf_lo(u.y), acc[2]);
    acc[3] = fmaf(q, bf_hi(u.y), acc[3]);
    acc[4] = fmaf(q, bf_lo(u.z), acc[4]);
    acc[5] = fmaf(q, bf_hi(u.z), acc[5]);
    acc[6] = fmaf(q, bf_lo(u.w), acc[6]);
    acc[7] = fmaf(q, bf_hi(u.w), acc[7]);
}

// ---------------- fused dtype conversion pre-pass ----------------
// section 0: x -> Xb (N*8 chunks of 8), section 1: W0 -> Wt0, section 2: W1 -> Wt1

__global__ void k_cvt_all(const float* __restrict__ x,
                          const float* __restrict__ W0,
                          const float* __restrict__ W1,
                          ushort* __restrict__ Xb,
                          ushort* __restrict__ Wt0,
                          ushort* __restrict__ Wt1, int N) {
    int i = blockIdx.x * blockDim.x + threadIdx.x;
    const int nx = N * 8;
    if (i < nx) {
        float4 a = *reinterpret_cast<const float4*>(x + (size_t)i * 8);
        float4 b = *reinterpret_cast<const float4*>(x + (size_t)i * 8 + 4);
        ushort u[8] = {f2bf(a.x), f2bf(a.y), f2bf(a.z), f2bf(a.w),
                       f2bf(b.x), f2bf(b.y), f2bf(b.z), f2bf(b.w)};
        *reinterpret_cast<uint4*>(Xb + (size_t)i * 8) = *reinterpret_cast<const uint4*>(u);
        return;
    }
    i -= nx;
    if (i < 64 * 256) {
        int k = i >> 8, c = i & 255;
        Wt0[(size_t)c * 64 + k] = f2bf(W0[i]);
        return;
    }
    i -= 64 * 256;
    if (i < 256 * 256) {
        int k = i >> 8, c = i & 255;
        Wt1[(size_t)c * 256 + k] = f2bf(W1[i]);
    }
}

// ---------------- CSR build ----------------

__global__ void k_hist(const int* __restrict__ ei, int E, int N, int* __restrict__ cnt) {
    int i = blockIdx.x * blockDim.x + threadIdx.x;
    if (i >= E + N) return;
    int dst = (i < E) ? ei[E + i] : (i - E);
    atomicAdd(&cnt[dst], 1);
}

__global__ __launch_bounds__(1024) void k_scan1(const int* __restrict__ cnt,
                                                int* __restrict__ offs,
                                                int* __restrict__ bsum, int n) {
    __shared__ int wsum[16];
    const int lane = threadIdx.x & 63;
    const int w = threadIdx.x >> 6;
    int i = blockIdx.x * 1024 + threadIdx.x;
    int v = (i < n) ? cnt[i] : 0;
#pragma unroll
    for (int off = 1; off < 64; off <<= 1) {
        int u = __shfl_up(v, off);
        if (lane >= off) v += u;
    }
    if (lane == 63) wsum[w] = v;
    __syncthreads();
    if (w == 0) {
        int x = (lane < 16) ? wsum[lane] : 0;
#pragma unroll
        for (int off = 1; off < 16; off <<= 1) {
            int u = __shfl_up(x, off);
            if (lane >= off) x += u;
        }
        if (lane < 16) wsum[lane] = x;
    }
    __syncthreads();
    v += (w > 0) ? wsum[w - 1] : 0;
    if (i < n) offs[i + 1] = v;
    if (threadIdx.x == 1023) bsum[blockIdx.x] = v;
}

__global__ __launch_bounds__(1024) void k_scan2(const int* __restrict__ bsum,
                                                int* __restrict__ bcarry, int nb) {
    __shared__ int wsum[16];
    const int lane = threadIdx.x & 63;
    const int w = threadIdx.x >> 6;
    int v0 = ((int)threadIdx.x < nb) ? bsum[threadIdx.x] : 0;
    int v = v0;
#pragma unroll
    for (int off = 1; off < 64; off <<= 1) {
        int u = __shfl_up(v, off);
        if (lane >= off) v += u;
    }
    if (lane == 63) wsum[w] = v;
    __syncthreads();
    if (w == 0) {
        int x = (lane < 16) ? wsum[lane] : 0;
#pragma unroll
        for (int off = 1; off < 16; off <<= 1) {
            int u = __shfl_up(x, off);
            if (lane >= off) x += u;
        }
        if (lane < 16) wsum[lane] = x;
    }
    __syncthreads();
    v += (w > 0) ? wsum[w - 1] : 0;
    if ((int)threadIdx.x < nb) bcarry[threadIdx.x] = v - v0;
}

// finalize offs and also write cursor = segment starts
__global__ void k_scan3(int* __restrict__ offs, const int* __restrict__ bcarry,
                        int* __restrict__ cursor, int n) {
    int i = blockIdx.x * blockDim.x + threadIdx.x;
    if (i == 0) { offs[0] = 0; cursor[0] = 0; }
    if (i < n) {
        int v = offs[i + 1] + bcarry[i >> 10];
        offs[i + 1] = v;
        if (i + 1 < n) cursor[i + 1] = v;
    }
}

__global__ void k_scatter(const int* __restrict__ ei, int E, int N,
                          int* __restrict__ cursor, int* __restrict__ csr) {
    int i = blockIdx.x * blockDim.x + threadIdx.x;
    if (i >= E + N) return;
    int src, dst;
    if (i < E) { src = ei[i]; dst = ei[E + i]; }
    else       { src = i - E; dst = i - E; }
    int pos = atomicAdd(&cursor[dst], 1);
    csr[pos] = src;
}

// ---------------- MFMA GEMM: h = Xb * W  (+ fused s,t scores) ----------------
// Xb: [N][K] bf16, Wt: [256][K] bf16 (W transposed), h: [N][256] bf16,
// s,t: [N][4] fp32.  Block = 256 thr (4 waves); block covers 64 rows x 64 cols.
// mfma_f32_16x16x32_bf16: A/B lane l&15 = row/col, l>>4 = k-octet (16B);
// C col = l&15, row = (l>>4)*4 + reg.

template <int K>
__global__ __launch_bounds__(256, 2) void k_gemm_mfma(
    const ushort* __restrict__ Xb, const ushort* __restrict__ Wt,
    const float* __restrict__ a_s, const float* __restrict__ a_d,
    ushort* __restrict__ h, float* __restrict__ s, float* __restrict__ t, int N)
{
    constexpr int KC = K / 32;
    const int tid = threadIdx.x;
    const int w = tid >> 6;
    const int l = tid & 63;
    const int lr = l & 15;
    const int lk = l >> 4;
    const int slice = blockIdx.x & 3;
    const int rowblk = blockIdx.x >> 2;
    const int row0 = rowblk * 64 + w * 16;

    short8 b[4][KC];
#pragma unroll
    for (int ct = 0; ct < 4; ++ct) {
        const ushort* wp = Wt + (size_t)(slice * 64 + ct * 16 + lr) * K + lk * 8;
#pragma unroll
        for (int kc = 0; kc < KC; ++kc)
            b[ct][kc] = *reinterpret_cast<const short8*>(wp + kc * 32);
    }

    int arow = row0 + lr;
    arow = (arow < N) ? arow : (N - 1);
    const ushort* xp = Xb + (size_t)arow * K + lk * 8;
    short8 a[KC];
#pragma unroll
    for (int kc = 0; kc < KC; ++kc)
        a[kc] = *reinterpret_cast<const short8*>(xp + kc * 32);

    f32x4 acc[4];
#pragma unroll
    for (int ct = 0; ct < 4; ++ct) acc[ct] = (f32x4){0.f, 0.f, 0.f, 0.f};

#pragma unroll
    for (int ct = 0; ct < 4; ++ct)
#pragma unroll
        for (int kc = 0; kc < KC; ++kc)
            acc[ct] = __builtin_amdgcn_mfma_f32_16x16x32_bf16(a[kc], b[ct][kc], acc[ct], 0, 0, 0);

    float asv[4], adv[4];
#pragma unroll
    for (int ct = 0; ct < 4; ++ct) {
        asv[ct] = a_s[slice * 64 + ct * 16 + lr];
        adv[ct] = a_d[slice * 64 + ct * 16 + lr];
    }
    float ps[4] = {0.f, 0.f, 0.f, 0.f}, pt[4] = {0.f, 0.f, 0.f, 0.f};
#pragma unroll
    for (int j = 0; j < 4; ++j) {
        int row = row0 + lk * 4 + j;
        bool ok = row < N;
#pragma unroll
        for (int ct = 0; ct < 4; ++ct) {
            float v = acc[ct][j];
            ps[j] = fmaf(v, asv[ct], ps[j]);
            pt[j] = fmaf(v, adv[ct], pt[j]);
            if (ok) h[(size_t)row * 256 + slice * 64 + ct * 16 + lr] = f2bf(v);
        }
    }
#pragma unroll
    for (int j = 0; j < 4; ++j) {
#pragma unroll
        for (int o = 1; o < 16; o <<= 1) {
            ps[j] += __shfl_xor(ps[j], o);
            pt[j] += __shfl_xor(pt[j], o);
        }
    }
    if (lr == 0) {
#pragma unroll
        for (int j = 0; j < 4; ++j) {
            int row = row0 + lk * 4 + j;
            if (row < N) {
                s[(size_t)row * 4 + slice] = ps[j];
                t[(size_t)row * 4 + slice] = pt[j];
            }
        }
    }
}

// ---------------- aggregation (+ bias + LayerNorm + ELU) ----------------
// TWO nodes per wave: 32 lanes per node, lane owns 8 channels (16B bf16).
// head = (lane&31)>>3. Online softmax, 32-edge chunks; p/byte-offsets parked
// in LDS (pad lanes carry p=0, off=0 -> row-0 loads, harmless).
// FUSE_W2: fold the 256->1 output projection into the epilogue (layer 1).

template <bool FUSE_W2>
__global__ __launch_bounds__(256) void k_agg_ln_elu(
    const int* __restrict__ offs, const int* __restrict__ csr,
    const float* __restrict__ s, const float* __restrict__ t,
    const ushort* __restrict__ h, const float* __restrict__ bias,
    const float* __restrict__ lng, const float* __restrict__ lnb,
    ushort* __restrict__ Y, const float* __restrict__ W2,
    float* __restrict__ h2, int N)
{
    __shared__ float p_s[4][2][32][4];
    __shared__ int off_s[4][2][32];

    const int tid = threadIdx.x;
    const int wid = tid >> 6;
    const int lane = tid & 63;
    const int half = lane >> 5;
    const int lh = lane & 31;
    const int n = blockIdx.x * 8 + wid * 2 + half;
    if (n >= N) return;
    const int head = lh >> 3;
    const int c0 = lh * 8;

    const float4 t4 = *reinterpret_cast<const float4*>(t + (size_t)n * 4);
    const int beg = offs[n], end = offs[n + 1];

    float4 m4 = make_float4(-1e30f, -1e30f, -1e30f, -1e30f);
    float4 den4 = make_float4(0.f, 0.f, 0.f, 0.f);
    float acc[8] = {0.f, 0.f, 0.f, 0.f, 0.f, 0.f, 0.f, 0.f};

    const char* hb = reinterpret_cast<const char*>(h) + lh * 16;
    float* pp = &p_s[wid][half][0][0];
    int* op = &off_s[wid][half][0];

    for (int base = beg; base < end; base += 32) {
        const int cnt = min(32, end - base);
        int src = 0;
        float4 e4 = make_float4(-1e30f, -1e30f, -1e30f, -1e30f);
        if (lh < cnt) {
            src = csr[base + lh];
            float4 sv = *reinterpret_cast<const float4*>(s + (size_t)src * 4);
            float ex = sv.x + t4.x, ey = sv.y + t4.y, ez = sv.z + t4.z, ew = sv.w + t4.w;
            e4.x = fmaxf(ex, NEG_SLOPE * ex);
            e4.y = fmaxf(ey, NEG_SLOPE * ey);
            e4.z = fmaxf(ez, NEG_SLOPE * ez);
            e4.w = fmaxf(ew, NEG_SLOPE * ew);
        }
        float4 bm = e4;
#pragma unroll
        for (int off = 1; off < 32; off <<= 1) {
            bm.x = fmaxf(bm.x, __shfl_xor(bm.x, off));
            bm.y = fmaxf(bm.y, __shfl_xor(bm.y, off));
            bm.z = fmaxf(bm.z, __shfl_xor(bm.z, off));
            bm.w = fmaxf(bm.w, __shfl_xor(bm.w, off));
        }
        float4 newm = make_float4(fmaxf(m4.x, bm.x), fmaxf(m4.y, bm.y),
                                  fmaxf(m4.z, bm.z), fmaxf(m4.w, bm.w));
        float4 sc4 = make_float4(__expf(m4.x - newm.x), __expf(m4.y - newm.y),
                                 __expf(m4.z - newm.z), __expf(m4.w - newm.w));
        m4 = newm;
        float sch = pick4(sc4, head);
#pragma unroll
        for (int c = 0; c < 8; ++c) acc[c] *= sch;
        float4 p4 = make_float4(__expf(e4.x - newm.x), __expf(e4.y - newm.y),
                                __expf(e4.z - newm.z), __expf(e4.w - newm.w));
        den4.x = den4.x * sc4.x + p4.x;
        den4.y = den4.y * sc4.y + p4.y;
        den4.z = den4.z * sc4.z + p4.z;
        den4.w = den4.w * sc4.w + p4.w;

        *reinterpret_cast<float4*>(&p_s[wid][half][lh][0]) = p4;
        op[lh] = src << 9;              // byte offset of h row
        asm volatile("s_waitcnt lgkmcnt(0)" ::: "memory");

        // padded gather, 4 edges per iteration (pad entries have p == 0)
        for (int j0 = 0; j0 < cnt; j0 += 4) {
            int o0 = op[j0 + 0];
            int o1 = op[j0 + 1];
            int o2 = op[j0 + 2];
            int o3 = op[j0 + 3];
            float q0 = pp[(j0 + 0) * 4 + head];
            float q1 = pp[(j0 + 1) * 4 + head];
            float q2 = pp[(j0 + 2) * 4 + head];
            float q3 = pp[(j0 + 3) * 4 + head];
            uint4 u0 = *reinterpret_cast<const uint4*>(hb + o0);
            uint4 u1 = *reinterpret_cast<const uint4*>(hb + o1);
            uint4 u2 = *reinterpret_cast<const uint4*>(hb + o2);
            uint4 u3 = *reinterpret_cast<const uint4*>(hb + o3);
            fma8(u0, q0, acc);
            fma8(u1, q1, acc);
            fma8(u2, q2, acc);
            fma8(u3, q3, acc);
        }
    }

    float4 dsum = den4;
#pragma unroll
    for (int off = 1; off < 32; off <<= 1) {
        dsum.x += __shfl_xor(dsum.x, off);
        dsum.y += __shfl_xor(dsum.y, off);
        dsum.z += __shfl_xor(dsum.z, off);
        dsum.w += __shfl_xor(dsum.w, off);
    }
    const float inv = 1.0f / pick4(dsum, head);
    float4 bv0 = *reinterpret_cast<const float4*>(bias + c0);
    float4 bv1 = *reinterpret_cast<const float4*>(bias + c0 + 4);
    float v[8];
    v[0] = acc[0] * inv + bv0.x; v[1] = acc[1] * inv + bv0.y;
    v[2] = acc[2] * inv + bv0.z; v[3] = acc[3] * inv + bv0.w;
    v[4] = acc[4] * inv + bv1.x; v[5] = acc[5] * inv + bv1.y;
    v[6] = acc[6] * inv + bv1.z; v[7] = acc[7] * inv + bv1.w;

    float sum = 0.f;
#pragma unroll
    for (int c = 0; c < 8; ++c) sum += v[c];
#pragma unroll
    for (int off = 1; off < 32; off <<= 1) sum += __shfl_xor(sum, off);
    float mu = sum * (1.0f / 256.0f);
    float d[8], vs = 0.f;
#pragma unroll
    for (int c = 0; c < 8; ++c) { d[c] = v[c] - mu; vs = fmaf(d[c], d[c], vs); }
#pragma unroll
    for (int off = 1; off < 32; off <<= 1) vs += __shfl_xor(vs, off);
    float rstd = rsqrtf(vs * (1.0f / 256.0f) + LN_EPS);
    float4 gv0 = *reinterpret_cast<const float4*>(lng + c0);
    float4 gv1 = *reinterpret_cast<const float4*>(lng + c0 + 4);
    float4 bb0 = *reinterpret_cast<const float4*>(lnb + c0);
    float4 bb1 = *reinterpret_cast<const float4*>(lnb + c0 + 4);
    float g[8] = {gv0.x, gv0.y, gv0.z, gv0.w, gv1.x, gv1.y, gv1.z, gv1.w};
    float bbv[8] = {bb0.x, bb0.y, bb0.z, bb0.w, bb1.x, bb1.y, bb1.z, bb1.w};
    float o[8];
#pragma unroll
    for (int c = 0; c < 8; ++c) {
        float val = fmaf(d[c] * rstd, g[c], bbv[c]);
        o[c] = (val > 0.f) ? val : (__expf(val) - 1.0f);
    }

    if (FUSE_W2) {
        float4 wv0 = *reinterpret_cast<const float4*>(W2 + c0);
        float4 wv1 = *reinterpret_cast<const float4*>(W2 + c0 + 4);
        float wv[8] = {wv0.x, wv0.y, wv0.z, wv0.w, wv1.x, wv1.y, wv1.z, wv1.w};
        float p = 0.f;
#pragma unroll
        for (int c = 0; c < 8; ++c) p = fmaf(o[c], wv[c], p);
#pragma unroll
        for (int off = 1; off < 32; off <<= 1) p += __shfl_xor(p, off);
        if (lh == 0) h2[n] = p;
    } else {
        ushort yo[8];
#pragma unroll
        for (int c = 0; c < 8; ++c) yo[c] = f2bf(o[c]);
        *reinterpret_cast<uint4*>(Y + (size_t)n * 256 + c0) =
            *reinterpret_cast<const uint4*>(yo);
    }
}

// ---------------- layer 2 aggregation (H=1,C=1): 4 nodes/wave ----------------

__global__ __launch_bounds__(256) void k_agg2(
    const int* __restrict__ offs, const int* __restrict__ csr,
    const float* __restrict__ h2,
    const float* __restrict__ as2, const float* __restrict__ ad2,
    const float* __restrict__ b2, float* __restrict__ out, int N)
{
    const int tid = threadIdx.x;
    const int wid = tid >> 6;
    const int lane = tid & 63;
    const int quarter = lane >> 4;
    const int lq = lane & 15;
    const int n = blockIdx.x * 16 + wid * 4 + quarter;
    if (n >= N) return;
    const float asv = as2[0], adv = ad2[0];
    const float tval = adv * h2[n];
    const int beg = offs[n], end = offs[n + 1];

    float m = -1e30f, den = 0.f, num = 0.f;
    for (int i = beg + lq; i < end; i += 16) {
        float hv = h2[csr[i]];
        float e = fmaf(asv, hv, tval);
        e = fmaxf(e, NEG_SLOPE * e);
        float nm = fmaxf(m, e);
        float sc = __expf(m - nm);
        float p = __expf(e - nm);
        den = den * sc + p;
        num = fmaf(num, sc, p * hv);
        m = nm;
    }
#pragma unroll
    for (int o = 1; o < 16; o <<= 1) {
        float m2 = __shfl_xor(m, o);
        float d2 = __shfl_xor(den, o);
        float n2 = __shfl_xor(num, o);
        float nm = fmaxf(m, m2);
        float sA = __expf(m - nm);
        float sB = __expf(m2 - nm);
        den = den * sA + d2 * sB;
        num = num * sA + n2 * sB;
        m = nm;
    }
    if (lq == 0) out[n] = num / den + b2[0];
}

// ---------------- launch ----------------

extern "C" void kernel_launch(void* const* d_in, const int* in_sizes, int n_in,
                              void* d_out, int out_size, void* d_ws, size_t ws_size,
                              hipStream_t stream) {
    const float* x   = (const float*)d_in[0];
    const int*   ei  = (const int*)d_in[1];
    const float* W0  = (const float*)d_in[2];
    const float* as0 = (const float*)d_in[3];
    const float* ad0 = (const float*)d_in[4];
    const float* b0  = (const float*)d_in[5];
    const float* W1  = (const float*)d_in[6];
    const float* as1 = (const float*)d_in[7];
    const float* ad1 = (const float*)d_in[8];
    const float* b1  = (const float*)d_in[9];
    const float* W2  = (const float*)d_in[10];
    const float* as2 = (const float*)d_in[11];
    const float* ad2 = (const float*)d_in[12];
    const float* b2  = (const float*)d_in[13];
    const float* lng = (const float*)d_in[14];
    const float* lnb = (const float*)d_in[15];

    const int N = in_sizes[0] / 64;
    const int E = in_sizes[1] / 2;
    const int TOT = E + N;
    const int NB = (N + 1023) / 1024;

    char* w = (char*)d_ws;
    auto alloc = [&](size_t bytes) -> void* {
        void* p = (void*)w;
        w += (bytes + 255) & ~(size_t)255;
        return p;
    };
    int*    cnt    = (int*)alloc(sizeof(int) * N);
    int*    offs   = (int*)alloc(sizeof(int) * (N + 1));
    int*    cursor = (int*)alloc(sizeof(int) * N);
    int*    csr    = (int*)alloc(sizeof(int) * TOT);
    int*    bsum   = (int*)alloc(sizeof(int) * (NB + 1));
    int*    bcarry = (int*)alloc(sizeof(int) * (NB + 1));
    float*  sbuf   = (float*)alloc(sizeof(float) * N * 4);
    float*  tbuf   = (float*)alloc(sizeof(float) * N * 4);
    ushort* Xb     = (ushort*)alloc(sizeof(ushort) * (size_t)N * 64);
    ushort* Wt0    = (ushort*)alloc(sizeof(ushort) * 256 * 64);
    ushort* Wt1    = (ushort*)alloc(sizeof(ushort) * 256 * 256);
    ushort* hbf    = (ushort*)alloc(sizeof(ushort) * (size_t)N * 256);
    ushort* Yb     = (ushort*)alloc(sizeof(ushort) * (size_t)N * 256);
    float*  h2     = (float*)alloc(sizeof(float) * N);
    float*  out    = (float*)d_out;

    // dtype pre-pass (fused) + zero-init for histogram
    hipMemsetAsync(cnt, 0, sizeof(int) * N, stream);
    const int cvt_tot = N * 8 + 64 * 256 + 256 * 256;
    k_cvt_all<<<(cvt_tot + 255) / 256, 256, 0, stream>>>(x, W0, W1, Xb, Wt0, Wt1, N);

    // CSR build
    k_hist<<<(TOT + 255) / 256, 256, 0, stream>>>(ei, E, N, cnt);
    k_scan1<<<NB, 1024, 0, stream>>>(cnt, offs, bsum, N);
    k_scan2<<<1, 1024, 0, stream>>>(bsum, bcarry, NB);
    k_scan3<<<(N + 255) / 256, 256, 0, stream>>>(offs, bcarry, cursor, N);
    k_scatter<<<(TOT + 255) / 256, 256, 0, stream>>>(ei, E, N, cursor, csr);

    const int gemm_grid = ((N + 63) / 64) * 4;
    const int node_grid8 = (N + 7) / 8;
    const int node_grid16 = (N + 15) / 16;

    // layer 0
    k_gemm_mfma<64><<<gemm_grid, 256, 0, stream>>>(Xb, Wt0, as0, ad0, hbf, sbuf, tbuf, N);
    k_agg_ln_elu<false><<<node_grid8, 256, 0, stream>>>(offs, csr, sbuf, tbuf, hbf,
                                                        b0, lng, lnb, Yb, nullptr, nullptr, N);
    // layer 1 (+ fused 256->1 projection)
    k_gemm_mfma<256><<<gemm_grid, 256, 0, stream>>>(Yb, Wt1, as1, ad1, hbf, sbuf, tbuf, N);
    k_agg_ln_elu<true><<<node_grid8, 256, 0, stream>>>(offs, csr, sbuf, tbuf, hbf,
                                                       b1, lng, lnb, nullptr, W2, h2, N);
    // layer 2
    k_agg2<<<node_grid16, 256, 0, stream>>>(offs, csr, h2, as2, ad2, b2, out, N);
}

// Round 7
// 289.791 us; speedup vs baseline: 2.6539x; 1.1202x over previous
//
#include <hip/hip_runtime.h>
#include <math.h>

constexpr float NEG_SLOPE = 0.2f;
constexpr float LN_EPS = 1e-5f;

typedef __attribute__((ext_vector_type(8))) short short8;   // bf16x8 MFMA frag
typedef __attribute__((ext_vector_type(4))) float f32x4;    // MFMA acc

__device__ inline ushort f2bf(float f) {        // fp32 -> bf16 RTN-even
    uint u = __float_as_uint(f);
    u += 0x7fffu + ((u >> 16) & 1u);
    return (ushort)(u >> 16);
}
__device__ inline float bf_lo(uint u) { return __uint_as_float(u << 16); }
__device__ inline float bf_hi(uint u) { return __uint_as_float(u & 0xffff0000u); }

__device__ inline float pick4(float4 v, int h) {
    float r = v.x;
    r = (h == 1) ? v.y : r;
    r = (h == 2) ? v.z : r;
    r = (h == 3) ? v.w : r;
    return r;
}

__device__ inline void fma8(const uint4& u, float q, float acc[8]) {
    acc[0] = fmaf(q, bf_lo(u.x), acc[0]);
    acc[1] = fmaf(q, bf_hi(u.x), acc[1]);
    acc[2] = fmaf(q, bf_lo(u.y), acc[2]);
    acc[3] = fmaf(q, bf_hi(u.y), acc[3]);
    acc[4] = fmaf(q, bf_lo(u.z), acc[4]);
    acc[5] = fmaf(q, bf_hi(u.z), acc[5]);
    acc[6] = fmaf(q, bf_lo(u.w), acc[6]);
    acc[7] = fmaf(q, bf_hi(u.w), acc[7]);
}

// ---------------- fused dtype conversion pre-pass ----------------

__global__ void k_cvt_all(const float* __restrict__ x,
                          const float* __restrict__ W0,
                          const float* __restrict__ W1,
                          ushort* __restrict__ Xb,
                          ushort* __restrict__ Wt0,
                          ushort* __restrict__ Wt1, int N) {
    int i = blockIdx.x * blockDim.x + threadIdx.x;
    const int nx = N * 8;
    if (i < nx) {
        float4 a = *reinterpret_cast<const float4*>(x + (size_t)i * 8);
        float4 b = *reinterpret_cast<const float4*>(x + (size_t)i * 8 + 4);
        ushort u[8] = {f2bf(a.x), f2bf(a.y), f2bf(a.z), f2bf(a.w),
                       f2bf(b.x), f2bf(b.y), f2bf(b.z), f2bf(b.w)};
        *reinterpret_cast<uint4*>(Xb + (size_t)i * 8) = *reinterpret_cast<const uint4*>(u);
        return;
    }
    i -= nx;
    if (i < 64 * 256) {
        int k = i >> 8, c = i & 255;
        Wt0[(size_t)c * 64 + k] = f2bf(W0[i]);
        return;
    }
    i -= 64 * 256;
    if (i < 256 * 256) {
        int k = i >> 8, c = i & 255;
        Wt1[(size_t)c * 256 + k] = f2bf(W1[i]);
    }
}

// ---------------- CSR build ----------------

__global__ void k_hist(const int* __restrict__ ei, int E, int N, int* __restrict__ cnt) {
    int i = blockIdx.x * blockDim.x + threadIdx.x;
    if (i >= E + N) return;
    int dst = (i < E) ? ei[E + i] : (i - E);
    atomicAdd(&cnt[dst], 1);
}

__global__ __launch_bounds__(1024) void k_scan1(const int* __restrict__ cnt,
                                                int* __restrict__ offs,
                                                int* __restrict__ bsum, int n) {
    __shared__ int wsum[16];
    const int lane = threadIdx.x & 63;
    const int w = threadIdx.x >> 6;
    int i = blockIdx.x * 1024 + threadIdx.x;
    int v = (i < n) ? cnt[i] : 0;
#pragma unroll
    for (int off = 1; off < 64; off <<= 1) {
        int u = __shfl_up(v, off);
        if (lane >= off) v += u;
    }
    if (lane == 63) wsum[w] = v;
    __syncthreads();
    if (w == 0) {
        int x = (lane < 16) ? wsum[lane] : 0;
#pragma unroll
        for (int off = 1; off < 16; off <<= 1) {
            int u = __shfl_up(x, off);
            if (lane >= off) x += u;
        }
        if (lane < 16) wsum[lane] = x;
    }
    __syncthreads();
    v += (w > 0) ? wsum[w - 1] : 0;
    if (i < n) offs[i + 1] = v;
    if (threadIdx.x == 1023) bsum[blockIdx.x] = v;
}

__global__ __launch_bounds__(1024) void k_scan2(const int* __restrict__ bsum,
                                                int* __restrict__ bcarry, int nb) {
    __shared__ int wsum[16];
    const int lane = threadIdx.x & 63;
    const int w = threadIdx.x >> 6;
    int v0 = ((int)threadIdx.x < nb) ? bsum[threadIdx.x] : 0;
    int v = v0;
#pragma unroll
    for (int off = 1; off < 64; off <<= 1) {
        int u = __shfl_up(v, off);
        if (lane >= off) v += u;
    }
    if (lane == 63) wsum[w] = v;
    __syncthreads();
    if (w == 0) {
        int x = (lane < 16) ? wsum[lane] : 0;
#pragma unroll
        for (int off = 1; off < 16; off <<= 1) {
            int u = __shfl_up(x, off);
            if (lane >= off) x += u;
        }
        if (lane < 16) wsum[lane] = x;
    }
    __syncthreads();
    v += (w > 0) ? wsum[w - 1] : 0;
    if ((int)threadIdx.x < nb) bcarry[threadIdx.x] = v - v0;
}

__global__ void k_scan3(int* __restrict__ offs, const int* __restrict__ bcarry,
                        int* __restrict__ cursor, int n) {
    int i = blockIdx.x * blockDim.x + threadIdx.x;
    if (i == 0) { offs[0] = 0; cursor[0] = 0; }
    if (i < n) {
        int v = offs[i + 1] + bcarry[i >> 10];
        offs[i + 1] = v;
        if (i + 1 < n) cursor[i + 1] = v;
    }
}

__global__ void k_scatter(const int* __restrict__ ei, int E, int N,
                          int* __restrict__ cursor, int* __restrict__ csr) {
    int i = blockIdx.x * blockDim.x + threadIdx.x;
    if (i >= E + N) return;
    int src, dst;
    if (i < E) { src = ei[i]; dst = ei[E + i]; }
    else       { src = i - E; dst = i - E; }
    int pos = atomicAdd(&cursor[dst], 1);
    csr[pos] = src;
}

// ---------------- MFMA GEMM: h = Xb * W  (+ fused s,t scores) ----------------
// Xb: [N][K] bf16, Wt: [256][K] bf16, h: [N][256] bf16, s,t: [N][4] fp32.
// Block = 4 waves. Each block owns ONE col-slice (64 cols) and a CHUNK of
// rbpc 64-row blocks; B frags live in registers across the chunk loop.
// XCD-aware mapping: xcd = bid&7 covers a contiguous row range x all 4
// slices -> A rows stay L2-resident per XCD.
// h is staged per-wave in padded LDS and stored as full 128B row-chunks
// (avoids partial-line write-allocate RMW).

template <int K>
__global__ __launch_bounds__(256, 2) void k_gemm_mfma(
    const ushort* __restrict__ Xb, const ushort* __restrict__ Wt,
    const float* __restrict__ a_s, const float* __restrict__ a_d,
    ushort* __restrict__ h, float* __restrict__ s, float* __restrict__ t,
    int N, int nrb, int cpx, int rbpc)
{
    constexpr int KC = K / 32;
    __shared__ ushort hstage[4][16][72];   // padded: row stride 144B

    const int tid = threadIdx.x;
    const int w = tid >> 6;
    const int l = tid & 63;
    const int lr = l & 15;
    const int lk = l >> 4;

    const int bid = blockIdx.x;
    const int xcd = bid & 7;
    const int j = bid >> 3;
    const int slice = j & 3;
    const int chunk = xcd * cpx + (j >> 2);
    const int rb0 = chunk * rbpc;
    const int rb1 = min(rb0 + rbpc, nrb);

    // B fragments once per block (live across chunk loop)
    short8 b[4][KC];
#pragma unroll
    for (int ct = 0; ct < 4; ++ct) {
        const ushort* wp = Wt + (size_t)(slice * 64 + ct * 16 + lr) * K + lk * 8;
#pragma unroll
        for (int kc = 0; kc < KC; ++kc)
            b[ct][kc] = *reinterpret_cast<const short8*>(wp + kc * 32);
    }

    float asv[4], adv[4];
#pragma unroll
    for (int ct = 0; ct < 4; ++ct) {
        asv[ct] = a_s[slice * 64 + ct * 16 + lr];
        adv[ct] = a_d[slice * 64 + ct * 16 + lr];
    }

    for (int rb = rb0; rb < rb1; ++rb) {
        const int row0 = rb * 64 + w * 16;

        int arow = row0 + lr;
        arow = (arow < N) ? arow : (N - 1);
        const ushort* xp = Xb + (size_t)arow * K + lk * 8;
        short8 a[KC];
#pragma unroll
        for (int kc = 0; kc < KC; ++kc)
            a[kc] = *reinterpret_cast<const short8*>(xp + kc * 32);

        f32x4 acc[4];
#pragma unroll
        for (int ct = 0; ct < 4; ++ct) acc[ct] = (f32x4){0.f, 0.f, 0.f, 0.f};
#pragma unroll
        for (int ct = 0; ct < 4; ++ct)
#pragma unroll
            for (int kc = 0; kc < KC; ++kc)
                acc[ct] = __builtin_amdgcn_mfma_f32_16x16x32_bf16(a[kc], b[ct][kc], acc[ct], 0, 0, 0);

        // fused s,t scores
        float ps[4] = {0.f, 0.f, 0.f, 0.f}, pt[4] = {0.f, 0.f, 0.f, 0.f};
#pragma unroll
        for (int jj = 0; jj < 4; ++jj) {
#pragma unroll
            for (int ct = 0; ct < 4; ++ct) {
                float v = acc[ct][jj];
                ps[jj] = fmaf(v, asv[ct], ps[jj]);
                pt[jj] = fmaf(v, adv[ct], pt[jj]);
            }
        }
#pragma unroll
        for (int jj = 0; jj < 4; ++jj) {
#pragma unroll
            for (int o = 1; o < 16; o <<= 1) {
                ps[jj] += __shfl_xor(ps[jj], o);
                pt[jj] += __shfl_xor(pt[jj], o);
            }
        }
        if (lr == 0) {
#pragma unroll
            for (int jj = 0; jj < 4; ++jj) {
                int row = row0 + lk * 4 + jj;
                if (row < N) {
                    s[(size_t)row * 4 + slice] = ps[jj];
                    t[(size_t)row * 4 + slice] = pt[jj];
                }
            }
        }

        // stage output tile in LDS (per-wave private), then coalesced store
#pragma unroll
        for (int ct = 0; ct < 4; ++ct)
#pragma unroll
            for (int jj = 0; jj < 4; ++jj)
                hstage[w][lk * 4 + jj][ct * 16 + lr] = f2bf(acc[ct][jj]);
        // compiler inserts lgkmcnt wait for the LDS RAW dependency below
#pragma unroll
        for (int hf = 0; hf < 2; ++hf) {
            int r = (l >> 3) + hf * 8;      // 0..15
            int ch = l & 7;                 // 16B chunk within 64 cols
            int grow = rb * 64 + w * 16 + r;
            uint4 v = *reinterpret_cast<const uint4*>(&hstage[w][r][ch * 8]);
            if (grow < N)
                *reinterpret_cast<uint4*>(h + (size_t)grow * 256 + slice * 64 + ch * 8) = v;
        }
    }
}

// ---------------- aggregation (+ bias + LayerNorm + ELU) ----------------
// TWO nodes per wave: 32 lanes per node, lane owns 8 channels (16B bf16).

template <bool FUSE_W2>
__global__ __launch_bounds__(256) void k_agg_ln_elu(
    const int* __restrict__ offs, const int* __restrict__ csr,
    const float* __restrict__ s, const float* __restrict__ t,
    const ushort* __restrict__ h, const float* __restrict__ bias,
    const float* __restrict__ lng, const float* __restrict__ lnb,
    ushort* __restrict__ Y, const float* __restrict__ W2,
    float* __restrict__ h2, int N)
{
    __shared__ float p_s[4][2][32][4];
    __shared__ int off_s[4][2][32];

    const int tid = threadIdx.x;
    const int wid = tid >> 6;
    const int lane = tid & 63;
    const int half = lane >> 5;
    const int lh = lane & 31;
    const int n = blockIdx.x * 8 + wid * 2 + half;
    if (n >= N) return;
    const int head = lh >> 3;
    const int c0 = lh * 8;

    const float4 t4 = *reinterpret_cast<const float4*>(t + (size_t)n * 4);
    const int beg = offs[n], end = offs[n + 1];

    float4 m4 = make_float4(-1e30f, -1e30f, -1e30f, -1e30f);
    float4 den4 = make_float4(0.f, 0.f, 0.f, 0.f);
    float acc[8] = {0.f, 0.f, 0.f, 0.f, 0.f, 0.f, 0.f, 0.f};

    const char* hb = reinterpret_cast<const char*>(h) + lh * 16;
    float* pp = &p_s[wid][half][0][0];
    int* op = &off_s[wid][half][0];

    for (int base = beg; base < end; base += 32) {
        const int cnt = min(32, end - base);
        int src = 0;
        float4 e4 = make_float4(-1e30f, -1e30f, -1e30f, -1e30f);
        if (lh < cnt) {
            src = csr[base + lh];
            float4 sv = *reinterpret_cast<const float4*>(s + (size_t)src * 4);
            float ex = sv.x + t4.x, ey = sv.y + t4.y, ez = sv.z + t4.z, ew = sv.w + t4.w;
            e4.x = fmaxf(ex, NEG_SLOPE * ex);
            e4.y = fmaxf(ey, NEG_SLOPE * ey);
            e4.z = fmaxf(ez, NEG_SLOPE * ez);
            e4.w = fmaxf(ew, NEG_SLOPE * ew);
        }
        float4 bm = e4;
#pragma unroll
        for (int off = 1; off < 32; off <<= 1) {
            bm.x = fmaxf(bm.x, __shfl_xor(bm.x, off));
            bm.y = fmaxf(bm.y, __shfl_xor(bm.y, off));
            bm.z = fmaxf(bm.z, __shfl_xor(bm.z, off));
            bm.w = fmaxf(bm.w, __shfl_xor(bm.w, off));
        }
        float4 newm = make_float4(fmaxf(m4.x, bm.x), fmaxf(m4.y, bm.y),
                                  fmaxf(m4.z, bm.z), fmaxf(m4.w, bm.w));
        float4 sc4 = make_float4(__expf(m4.x - newm.x), __expf(m4.y - newm.y),
                                 __expf(m4.z - newm.z), __expf(m4.w - newm.w));
        m4 = newm;
        float sch = pick4(sc4, head);
#pragma unroll
        for (int c = 0; c < 8; ++c) acc[c] *= sch;
        float4 p4 = make_float4(__expf(e4.x - newm.x), __expf(e4.y - newm.y),
                                __expf(e4.z - newm.z), __expf(e4.w - newm.w));
        den4.x = den4.x * sc4.x + p4.x;
        den4.y = den4.y * sc4.y + p4.y;
        den4.z = den4.z * sc4.z + p4.z;
        den4.w = den4.w * sc4.w + p4.w;

        *reinterpret_cast<float4*>(&p_s[wid][half][lh][0]) = p4;
        op[lh] = src << 9;              // byte offset of h row
        asm volatile("s_waitcnt lgkmcnt(0)" ::: "memory");

        for (int j0 = 0; j0 < cnt; j0 += 4) {
            int o0 = op[j0 + 0];
            int o1 = op[j0 + 1];
            int o2 = op[j0 + 2];
            int o3 = op[j0 + 3];
            float q0 = pp[(j0 + 0) * 4 + head];
            float q1 = pp[(j0 + 1) * 4 + head];
            float q2 = pp[(j0 + 2) * 4 + head];
            float q3 = pp[(j0 + 3) * 4 + head];
            uint4 u0 = *reinterpret_cast<const uint4*>(hb + o0);
            uint4 u1 = *reinterpret_cast<const uint4*>(hb + o1);
            uint4 u2 = *reinterpret_cast<const uint4*>(hb + o2);
            uint4 u3 = *reinterpret_cast<const uint4*>(hb + o3);
            fma8(u0, q0, acc);
            fma8(u1, q1, acc);
            fma8(u2, q2, acc);
            fma8(u3, q3, acc);
        }
    }

    float4 dsum = den4;
#pragma unroll
    for (int off = 1; off < 32; off <<= 1) {
        dsum.x += __shfl_xor(dsum.x, off);
        dsum.y += __shfl_xor(dsum.y, off);
        dsum.z += __shfl_xor(dsum.z, off);
        dsum.w += __shfl_xor(dsum.w, off);
    }
    const float inv = 1.0f / pick4(dsum, head);
    float4 bv0 = *reinterpret_cast<const float4*>(bias + c0);
    float4 bv1 = *reinterpret_cast<const float4*>(bias + c0 + 4);
    float v[8];
    v[0] = acc[0] * inv + bv0.x; v[1] = acc[1] * inv + bv0.y;
    v[2] = acc[2] * inv + bv0.z; v[3] = acc[3] * inv + bv0.w;
    v[4] = acc[4] * inv + bv1.x; v[5] = acc[5] * inv + bv1.y;
    v[6] = acc[6] * inv + bv1.z; v[7] = acc[7] * inv + bv1.w;

    float sum = 0.f;
#pragma unroll
    for (int c = 0; c < 8; ++c) sum += v[c];
#pragma unroll
    for (int off = 1; off < 32; off <<= 1) sum += __shfl_xor(sum, off);
    float mu = sum * (1.0f / 256.0f);
    float d[8], vs = 0.f;
#pragma unroll
    for (int c = 0; c < 8; ++c) { d[c] = v[c] - mu; vs = fmaf(d[c], d[c], vs); }
#pragma unroll
    for (int off = 1; off < 32; off <<= 1) vs += __shfl_xor(vs, off);
    float rstd = rsqrtf(vs * (1.0f / 256.0f) + LN_EPS);
    float4 gv0 = *reinterpret_cast<const float4*>(lng + c0);
    float4 gv1 = *reinterpret_cast<const float4*>(lng + c0 + 4);
    float4 bb0 = *reinterpret_cast<const float4*>(lnb + c0);
    float4 bb1 = *reinterpret_cast<const float4*>(lnb + c0 + 4);
    float g[8] = {gv0.x, gv0.y, gv0.z, gv0.w, gv1.x, gv1.y, gv1.z, gv1.w};
    float bbv[8] = {bb0.x, bb0.y, bb0.z, bb0.w, bb1.x, bb1.y, bb1.z, bb1.w};
    float o[8];
#pragma unroll
    for (int c = 0; c < 8; ++c) {
        float val = fmaf(d[c] * rstd, g[c], bbv[c]);
        o[c] = (val > 0.f) ? val : (__expf(val) - 1.0f);
    }

    if (FUSE_W2) {
        float4 wv0 = *reinterpret_cast<const float4*>(W2 + c0);
        float4 wv1 = *reinterpret_cast<const float4*>(W2 + c0 + 4);
        float wv[8] = {wv0.x, wv0.y, wv0.z, wv0.w, wv1.x, wv1.y, wv1.z, wv1.w};
        float p = 0.f;
#pragma unroll
        for (int c = 0; c < 8; ++c) p = fmaf(o[c], wv[c], p);
#pragma unroll
        for (int off = 1; off < 32; off <<= 1) p += __shfl_xor(p, off);
        if (lh == 0) h2[n] = p;
    } else {
        ushort yo[8];
#pragma unroll
        for (int c = 0; c < 8; ++c) yo[c] = f2bf(o[c]);
        *reinterpret_cast<uint4*>(Y + (size_t)n * 256 + c0) =
            *reinterpret_cast<const uint4*>(yo);
    }
}

// ---------------- layer 2 aggregation (H=1,C=1): 4 nodes/wave ----------------

__global__ __launch_bounds__(256) void k_agg2(
    const int* __restrict__ offs, const int* __restrict__ csr,
    const float* __restrict__ h2,
    const float* __restrict__ as2, const float* __restrict__ ad2,
    const float* __restrict__ b2, float* __restrict__ out, int N)
{
    const int tid = threadIdx.x;
    const int wid = tid >> 6;
    const int lane = tid & 63;
    const int quarter = lane >> 4;
    const int lq = lane & 15;
    const int n = blockIdx.x * 16 + wid * 4 + quarter;
    if (n >= N) return;
    const float asv = as2[0], adv = ad2[0];
    const float tval = adv * h2[n];
    const int beg = offs[n], end = offs[n + 1];

    float m = -1e30f, den = 0.f, num = 0.f;
    for (int i = beg + lq; i < end; i += 16) {
        float hv = h2[csr[i]];
        float e = fmaf(asv, hv, tval);
        e = fmaxf(e, NEG_SLOPE * e);
        float nm = fmaxf(m, e);
        float sc = __expf(m - nm);
        float p = __expf(e - nm);
        den = den * sc + p;
        num = fmaf(num, sc, p * hv);
        m = nm;
    }
#pragma unroll
    for (int o = 1; o < 16; o <<= 1) {
        float m2 = __shfl_xor(m, o);
        float d2 = __shfl_xor(den, o);
        float n2 = __shfl_xor(num, o);
        float nm = fmaxf(m, m2);
        float sA = __expf(m - nm);
        float sB = __expf(m2 - nm);
        den = den * sA + d2 * sB;
        num = num * sA + n2 * sB;
        m = nm;
    }
    if (lq == 0) out[n] = num / den + b2[0];
}

// ---------------- launch ----------------

extern "C" void kernel_launch(void* const* d_in, const int* in_sizes, int n_in,
                              void* d_out, int out_size, void* d_ws, size_t ws_size,
                              hipStream_t stream) {
    const float* x   = (const float*)d_in[0];
    const int*   ei  = (const int*)d_in[1];
    const float* W0  = (const float*)d_in[2];
    const float* as0 = (const float*)d_in[3];
    const float* ad0 = (const float*)d_in[4];
    const float* b0  = (const float*)d_in[5];
    const float* W1  = (const float*)d_in[6];
    const float* as1 = (const float*)d_in[7];
    const float* ad1 = (const float*)d_in[8];
    const float* b1  = (const float*)d_in[9];
    const float* W2  = (const float*)d_in[10];
    const float* as2 = (const float*)d_in[11];
    const float* ad2 = (const float*)d_in[12];
    const float* b2  = (const float*)d_in[13];
    const float* lng = (const float*)d_in[14];
    const float* lnb = (const float*)d_in[15];

    const int N = in_sizes[0] / 64;
    const int E = in_sizes[1] / 2;
    const int TOT = E + N;
    const int NB = (N + 1023) / 1024;

    char* w = (char*)d_ws;
    auto alloc = [&](size_t bytes) -> void* {
        void* p = (void*)w;
        w += (bytes + 255) & ~(size_t)255;
        return p;
    };
    int*    cnt    = (int*)alloc(sizeof(int) * N);
    int*    offs   = (int*)alloc(sizeof(int) * (N + 1));
    int*    cursor = (int*)alloc(sizeof(int) * N);
    int*    csr    = (int*)alloc(sizeof(int) * TOT);
    int*    bsum   = (int*)alloc(sizeof(int) * (NB + 1));
    int*    bcarry = (int*)alloc(sizeof(int) * (NB + 1));
    float*  sbuf   = (float*)alloc(sizeof(float) * N * 4);
    float*  tbuf   = (float*)alloc(sizeof(float) * N * 4);
    ushort* Xb     = (ushort*)alloc(sizeof(ushort) * (size_t)N * 64);
    ushort* Wt0    = (ushort*)alloc(sizeof(ushort) * 256 * 64);
    ushort* Wt1    = (ushort*)alloc(sizeof(ushort) * 256 * 256);
    ushort* hbf    = (ushort*)alloc(sizeof(ushort) * (size_t)N * 256);
    ushort* Yb     = (ushort*)alloc(sizeof(ushort) * (size_t)N * 256);
    float*  h2     = (float*)alloc(sizeof(float) * N);
    float*  out    = (float*)d_out;

    // dtype pre-pass (fused) + zero-init for histogram
    hipMemsetAsync(cnt, 0, sizeof(int) * N, stream);
    const int cvt_tot = N * 8 + 64 * 256 + 256 * 256;
    k_cvt_all<<<(cvt_tot + 255) / 256, 256, 0, stream>>>(x, W0, W1, Xb, Wt0, Wt1, N);

    // CSR build
    k_hist<<<(TOT + 255) / 256, 256, 0, stream>>>(ei, E, N, cnt);
    k_scan1<<<NB, 1024, 0, stream>>>(cnt, offs, bsum, N);
    k_scan2<<<1, 1024, 0, stream>>>(bsum, bcarry, NB);
    k_scan3<<<(N + 255) / 256, 256, 0, stream>>>(offs, bcarry, cursor, N);
    k_scatter<<<(TOT + 255) / 256, 256, 0, stream>>>(ei, E, N, cursor, csr);

    // GEMM grid: 8 xcds x cpx chunks x 4 slices; each block does rbpc row-blocks
    const int nrb = (N + 63) / 64;
    const int cpx = 25;
    const int chunks = 8 * cpx;                 // 200
    const int rbpc = (nrb + chunks - 1) / chunks;  // 4 at N=50000
    const int gemm_grid = chunks * 4;           // 800
    const int node_grid8 = (N + 7) / 8;
    const int node_grid16 = (N + 15) / 16;

    // layer 0
    k_gemm_mfma<64><<<gemm_grid, 256, 0, stream>>>(Xb, Wt0, as0, ad0, hbf, sbuf, tbuf,
                                                   N, nrb, cpx, rbpc);
    k_agg_ln_elu<false><<<node_grid8, 256, 0, stream>>>(offs, csr, sbuf, tbuf, hbf,
                                                        b0, lng, lnb, Yb, nullptr, nullptr, N);
    // layer 1 (+ fused 256->1 projection)
    k_gemm_mfma<256><<<gemm_grid, 256, 0, stream>>>(Yb, Wt1, as1, ad1, hbf, sbuf, tbuf,
                                                    N, nrb, cpx, rbpc);
    k_agg_ln_elu<true><<<node_grid8, 256, 0, stream>>>(offs, csr, sbuf, tbuf, hbf,
                                                       b1, lng, lnb, nullptr, W2, h2, N);
    // layer 2
    k_agg2<<<node_grid16, 256, 0, stream>>>(offs, csr, h2, as2, ad2, b2, out, N);
}